// Round 1
// baseline (3698.726 us; speedup 1.0000x reference)
//
#include <hip/hip_runtime.h>

#define NN 100000
#define NE 640000
#define NR 3
#define DD 128

// ---------------- degree counting ----------------
__global__ __launch_bounds__(256) void degree_kernel(const int* __restrict__ src,
                                                     const int* __restrict__ dst,
                                                     int* __restrict__ cnt_out,
                                                     int* __restrict__ cnt_in) {
  int i = blockIdx.x * 256 + threadIdx.x;
  if (i >= NR * NE) return;
  int r = i / NE;
  atomicAdd(&cnt_out[r * NN + src[i]], 1);
  atomicAdd(&cnt_in[r * NN + dst[i]], 1);
}

__global__ __launch_bounds__(256) void rs_kernel(const int* __restrict__ cnt_out,
                                                 const int* __restrict__ cnt_in,
                                                 float* __restrict__ rs_out,
                                                 float* __restrict__ rs_in) {
  int i = blockIdx.x * 256 + threadIdx.x;
  if (i >= NR * NN) return;
  int co = cnt_out[i]; if (co < 1) co = 1;
  int ci = cnt_in[i]; if (ci < 1) ci = 1;
  rs_out[i] = rsqrtf((float)co);
  rs_in[i]  = rsqrtf((float)ci);
}

// ---------------- edge scatter: agg[r][dst] += x[src] * rs_out[r][src] ----------------
// 32 lanes per edge (float4 each), 8 edges per 256-thread block.
__global__ __launch_bounds__(256) void scatter_kernel(const float* __restrict__ x,
                                                      const int* __restrict__ src,
                                                      const int* __restrict__ dst,
                                                      const float* __restrict__ rs_out,
                                                      float* __restrict__ agg) {
  const int lane = threadIdx.x & 31;
  const int slot = threadIdx.x >> 5;
  int idx = blockIdx.x * 8 + slot;
  if (idx >= NR * NE) return;
  int r = idx / NE;
  int s = src[idx];
  int d = dst[idx];
  float sc = rs_out[r * NN + s];
  const float4 v = *(const float4*)&x[(size_t)s * DD + lane * 4];
  float* o = &agg[((size_t)r * NN + d) * DD + lane * 4];
  atomicAdd(o + 0, v.x * sc);
  atomicAdd(o + 1, v.y * sc);
  atomicAdd(o + 2, v.z * sc);
  atomicAdd(o + 3, v.w * sc);
}

// ---------------- GEMM: rel = (agg @ W_r) * rs_in + b_r   (in-place over agg) ----------
// Block: 64 rows x 128 cols, 256 threads, each thread 4 rows x 8 cols.
__global__ __launch_bounds__(256) void gemm_rel_kernel(const float* __restrict__ A,
                                                       const float* __restrict__ W,
                                                       const float* __restrict__ rs_in,
                                                       const float* __restrict__ bias,
                                                       float* __restrict__ C) {
  const int r = blockIdx.y;
  const int row0 = blockIdx.x * 64;
  __shared__ float As[64][33];
  __shared__ float Ws[32][128];
  const int tid = threadIdx.x;
  const int tx = tid & 15, ty = tid >> 4;
  float acc[4][8] = {};
  const float* Ag = A + (size_t)r * NN * DD;
  const float* Wg = W + r * DD * DD;
  for (int k0 = 0; k0 < DD; k0 += 32) {
#pragma unroll
    for (int p = 0; p < 2; ++p) {
      int rr = (tid >> 3) + p * 32;
      int cc = (tid & 7) * 4;
      int grow = row0 + rr; if (grow > NN - 1) grow = NN - 1;
      const float4 v = *(const float4*)&Ag[(size_t)grow * DD + k0 + cc];
      As[rr][cc] = v.x; As[rr][cc + 1] = v.y; As[rr][cc + 2] = v.z; As[rr][cc + 3] = v.w;
    }
#pragma unroll
    for (int p = 0; p < 4; ++p) {
      int rr = (tid >> 5) + p * 8;
      int cc = (tid & 31) * 4;
      *(float4*)&Ws[rr][cc] = *(const float4*)&Wg[(size_t)(k0 + rr) * DD + cc];
    }
    __syncthreads();
#pragma unroll
    for (int k = 0; k < 32; ++k) {
      float a[4], w[8];
#pragma unroll
      for (int i = 0; i < 4; ++i) a[i] = As[ty * 4 + i][k];
#pragma unroll
      for (int j = 0; j < 8; ++j) w[j] = Ws[k][tx * 8 + j];
#pragma unroll
      for (int i = 0; i < 4; ++i)
#pragma unroll
        for (int j = 0; j < 8; ++j)
          acc[i][j] = fmaf(a[i], w[j], acc[i][j]);
    }
    __syncthreads();
  }
#pragma unroll
  for (int i = 0; i < 4; ++i) {
    int grow = row0 + ty * 4 + i;
    if (grow >= NN) continue;
    float sc = rs_in[r * NN + grow];
    float o[8];
#pragma unroll
    for (int j = 0; j < 8; ++j) o[j] = acc[i][j] * sc + bias[r * DD + tx * 8 + j];
    float4* cp = (float4*)&C[((size_t)r * NN + grow) * DD + tx * 8];
    cp[0] = make_float4(o[0], o[1], o[2], o[3]);
    cp[1] = make_float4(o[4], o[5], o[6], o[7]);
  }
}

// ---------------- score GEMM: score[r,i] = sum_j tanh((rel @ Wa1)[j] + ba1[j]) * wa2[j] --
__global__ __launch_bounds__(256) void score_kernel(const float* __restrict__ A,
                                                    const float* __restrict__ Wa1,
                                                    const float* __restrict__ ba1,
                                                    const float* __restrict__ wa2,
                                                    float* __restrict__ score) {
  const int r = blockIdx.y;
  const int row0 = blockIdx.x * 64;
  __shared__ float As[64][33];
  __shared__ float Ws[32][128];
  const int tid = threadIdx.x;
  const int tx = tid & 15, ty = tid >> 4;
  float acc[4][8] = {};
  const float* Ag = A + (size_t)r * NN * DD;
  for (int k0 = 0; k0 < DD; k0 += 32) {
#pragma unroll
    for (int p = 0; p < 2; ++p) {
      int rr = (tid >> 3) + p * 32;
      int cc = (tid & 7) * 4;
      int grow = row0 + rr; if (grow > NN - 1) grow = NN - 1;
      const float4 v = *(const float4*)&Ag[(size_t)grow * DD + k0 + cc];
      As[rr][cc] = v.x; As[rr][cc + 1] = v.y; As[rr][cc + 2] = v.z; As[rr][cc + 3] = v.w;
    }
#pragma unroll
    for (int p = 0; p < 4; ++p) {
      int rr = (tid >> 5) + p * 8;
      int cc = (tid & 31) * 4;
      *(float4*)&Ws[rr][cc] = *(const float4*)&Wa1[(size_t)(k0 + rr) * DD + cc];
    }
    __syncthreads();
#pragma unroll
    for (int k = 0; k < 32; ++k) {
      float a[4], w[8];
#pragma unroll
      for (int i = 0; i < 4; ++i) a[i] = As[ty * 4 + i][k];
#pragma unroll
      for (int j = 0; j < 8; ++j) w[j] = Ws[k][tx * 8 + j];
#pragma unroll
      for (int i = 0; i < 4; ++i)
#pragma unroll
        for (int j = 0; j < 8; ++j)
          acc[i][j] = fmaf(a[i], w[j], acc[i][j]);
    }
    __syncthreads();
  }
#pragma unroll
  for (int i = 0; i < 4; ++i) {
    float p = 0.f;
#pragma unroll
    for (int j = 0; j < 8; ++j) {
      int c = tx * 8 + j;
      p += tanhf(acc[i][j] + ba1[c]) * wa2[c];
    }
    p += __shfl_xor(p, 1);
    p += __shfl_xor(p, 2);
    p += __shfl_xor(p, 4);
    p += __shfl_xor(p, 8);
    if (tx == 0) {
      int grow = row0 + ty * 4 + i;
      if (grow < NN) score[r * NN + grow] = p;
    }
  }
}

// ---------------- final: softmax over relations + weighted sum -------------------------
__global__ __launch_bounds__(256) void final_kernel(const float* __restrict__ rel,
                                                    const float* __restrict__ score,
                                                    float* __restrict__ out) {
  const int lane = threadIdx.x & 31;
  const int slot = threadIdx.x >> 5;
  int i = blockIdx.x * 8 + slot;
  if (i >= NN) return;
  float s0 = score[i], s1 = score[NN + i], s2 = score[2 * NN + i];
  float m = fmaxf(s0, fmaxf(s1, s2));
  float e0 = __expf(s0 - m), e1 = __expf(s1 - m), e2 = __expf(s2 - m);
  float inv = 1.f / (e0 + e1 + e2);
  e0 *= inv; e1 *= inv; e2 *= inv;
  size_t off = (size_t)i * DD + lane * 4;
  float4 v0 = *(const float4*)&rel[off];
  float4 v1 = *(const float4*)&rel[(size_t)NN * DD + off];
  float4 v2 = *(const float4*)&rel[2 * (size_t)NN * DD + off];
  float4 o;
  o.x = v0.x * e0 + v1.x * e1 + v2.x * e2;
  o.y = v0.y * e0 + v1.y * e1 + v2.y * e2;
  o.z = v0.z * e0 + v1.z * e1 + v2.z * e2;
  o.w = v0.w * e0 + v1.w * e1 + v2.w * e2;
  *(float4*)&out[off] = o;
}

extern "C" void kernel_launch(void* const* d_in, const int* in_sizes, int n_in,
                              void* d_out, int out_size, void* d_ws, size_t ws_size,
                              hipStream_t stream) {
  const float* x   = (const float*)d_in[0];
  const int*   src = (const int*)d_in[1];
  const int*   dst = (const int*)d_in[2];
  const float* W   = (const float*)d_in[3];
  const float* b   = (const float*)d_in[4];
  const float* Wa1 = (const float*)d_in[5];
  const float* ba1 = (const float*)d_in[6];
  const float* wa2 = (const float*)d_in[7];
  float* out = (float*)d_out;

  char* ws = (char*)d_ws;
  size_t off = 0;
  float* agg = (float*)(ws + off); off += (size_t)NR * NN * DD * 4;   // 153.6 MB
  int* cnt_out = (int*)(ws + off); off += (size_t)NR * NN * 4;
  int* cnt_in  = (int*)(ws + off); off += (size_t)NR * NN * 4;
  float* rs_out = (float*)(ws + off); off += (size_t)NR * NN * 4;
  float* rs_in  = (float*)(ws + off); off += (size_t)NR * NN * 4;
  float* score  = (float*)(ws + off); off += (size_t)NR * NN * 4;
  if (ws_size < off) return;  // fail loudly (output stays poisoned)

  hipMemsetAsync(agg, 0, (size_t)NR * NN * DD * 4, stream);
  hipMemsetAsync(cnt_out, 0, (size_t)NR * NN * 4 * 2, stream);  // cnt_out + cnt_in

  degree_kernel<<<(NR * NE + 255) / 256, 256, 0, stream>>>(src, dst, cnt_out, cnt_in);
  rs_kernel<<<(NR * NN + 255) / 256, 256, 0, stream>>>(cnt_out, cnt_in, rs_out, rs_in);
  scatter_kernel<<<NR * NE / 8, 256, 0, stream>>>(x, src, dst, rs_out, agg);
  dim3 g1((NN + 63) / 64, NR);
  gemm_rel_kernel<<<g1, 256, 0, stream>>>(agg, W, rs_in, b, agg);
  score_kernel<<<g1, 256, 0, stream>>>(agg, Wa1, ba1, wa2, score);
  final_kernel<<<NN / 8, 256, 0, stream>>>(agg, score, out);
}

// Round 2
// 831.346 us; speedup vs baseline: 4.4491x; 4.4491x over previous
//
#include <hip/hip_runtime.h>

#define NN 100000
#define NE 640000
#define NR 3
#define DD 128
#define NSEG (NR * NN)            // 300000 segments (relation, node)
#define SCAN_BLK 1024             // elements per scan block
#define NBLK ((NSEG + SCAN_BLK - 1) / SCAN_BLK)   // 293

// ---------------- degree counting ----------------
__global__ __launch_bounds__(256) void degree_kernel(const int* __restrict__ src,
                                                     const int* __restrict__ dst,
                                                     int* __restrict__ cnt_out,
                                                     int* __restrict__ cnt_in) {
  int i = blockIdx.x * 256 + threadIdx.x;
  if (i >= NR * NE) return;
  int r = i / NE;
  atomicAdd(&cnt_out[r * NN + src[i]], 1);
  atomicAdd(&cnt_in[r * NN + dst[i]], 1);
}

__global__ __launch_bounds__(256) void rs_kernel(const int* __restrict__ cnt_out,
                                                 const int* __restrict__ cnt_in,
                                                 float* __restrict__ rs_out,
                                                 float* __restrict__ rs_in) {
  int i = blockIdx.x * 256 + threadIdx.x;
  if (i >= NSEG) return;
  int co = cnt_out[i]; if (co < 1) co = 1;
  int ci = cnt_in[i]; if (ci < 1) ci = 1;
  rs_out[i] = rsqrtf((float)co);
  rs_in[i]  = rsqrtf((float)ci);
}

// ---------------- counting-sort scan (3 kernels) ----------------
__global__ __launch_bounds__(256) void scan1_kernel(const int* __restrict__ cnt,
                                                    int* __restrict__ offs,
                                                    int* __restrict__ blksum) {
  __shared__ int s[256];
  const int t = threadIdx.x;
  const int base = blockIdx.x * SCAN_BLK + t * 4;
  int v[4] = {0, 0, 0, 0};
#pragma unroll
  for (int j = 0; j < 4; ++j) { int i = base + j; if (i < NSEG) v[j] = cnt[i]; }
  const int tot = v[0] + v[1] + v[2] + v[3];
  s[t] = tot;
  __syncthreads();
  for (int d = 1; d < 256; d <<= 1) {
    int a = (t >= d) ? s[t - d] : 0;
    __syncthreads();
    s[t] += a;
    __syncthreads();
  }
  if (t == 255) blksum[blockIdx.x] = s[255];
  int run = s[t] - tot;  // exclusive prefix within block
#pragma unroll
  for (int j = 0; j < 4; ++j) {
    int i = base + j;
    if (i < NSEG) { offs[i] = run; run += v[j]; }
  }
}

__global__ __launch_bounds__(512) void scan2_kernel(int* __restrict__ blksum, int n) {
  __shared__ int s[512];
  const int t = threadIdx.x;
  int v = (t < n) ? blksum[t] : 0;
  s[t] = v;
  __syncthreads();
  for (int d = 1; d < 512; d <<= 1) {
    int a = (t >= d) ? s[t - d] : 0;
    __syncthreads();
    s[t] += a;
    __syncthreads();
  }
  if (t < n) blksum[t] = s[t] - v;  // exclusive
}

__global__ __launch_bounds__(256) void scan3_kernel(int* __restrict__ offs,
                                                    const int* __restrict__ blksum,
                                                    int* __restrict__ cursor) {
  int i = blockIdx.x * 256 + threadIdx.x;
  if (i < NSEG) {
    int o = offs[i] + blksum[i >> 10];
    offs[i] = o;
    cursor[i] = o;
  }
  if (i == 0) offs[NSEG] = NR * NE;
}

// ---------------- fill dst-sorted edge list ----------------
__global__ __launch_bounds__(256) void fill_kernel(const int* __restrict__ src,
                                                   const int* __restrict__ dst,
                                                   int* __restrict__ cursor,
                                                   int* __restrict__ esrc) {
  int i = blockIdx.x * 256 + threadIdx.x;
  if (i >= NR * NE) return;
  int r = i / NE;
  int seg = r * NN + dst[i];
  int pos = atomicAdd(&cursor[seg], 1);
  esrc[pos] = src[i];
}

// ---------------- gather aggregate: agg[seg] = sum_e x[esrc[e]] * rs_out[r][esrc[e]] ---
// One 64-lane wave per segment, float2 per lane.
__global__ __launch_bounds__(256) void aggregate_kernel(const float* __restrict__ x,
                                                        const int* __restrict__ esrc,
                                                        const int* __restrict__ offs,
                                                        const float* __restrict__ rs_out,
                                                        float* __restrict__ agg) {
  const int lane = threadIdx.x & 63;
  const int w = threadIdx.x >> 6;
  const int seg = blockIdx.x * 4 + w;
  if (seg >= NSEG) return;
  const int r = seg / NN;
  const int beg = offs[seg], end = offs[seg + 1];
  const float* rs = rs_out + r * NN;
  float2 acc = make_float2(0.f, 0.f);
  for (int e = beg; e < end; ++e) {
    int s = esrc[e];
    float sc = rs[s];
    float2 v = *(const float2*)&x[(size_t)s * DD + lane * 2];
    acc.x = fmaf(v.x, sc, acc.x);
    acc.y = fmaf(v.y, sc, acc.y);
  }
  *(float2*)&agg[(size_t)seg * DD + lane * 2] = acc;
}

// ---------------- GEMM: rel = (agg @ W_r) * rs_in + b_r   (in-place over agg) ----------
__global__ __launch_bounds__(256) void gemm_rel_kernel(const float* __restrict__ A,
                                                       const float* __restrict__ W,
                                                       const float* __restrict__ rs_in,
                                                       const float* __restrict__ bias,
                                                       float* __restrict__ C) {
  const int r = blockIdx.y;
  const int row0 = blockIdx.x * 64;
  __shared__ float As[64][33];
  __shared__ float Ws[32][128];
  const int tid = threadIdx.x;
  const int tx = tid & 15, ty = tid >> 4;
  float acc[4][8] = {};
  const float* Ag = A + (size_t)r * NN * DD;
  const float* Wg = W + r * DD * DD;
  for (int k0 = 0; k0 < DD; k0 += 32) {
#pragma unroll
    for (int p = 0; p < 2; ++p) {
      int rr = (tid >> 3) + p * 32;
      int cc = (tid & 7) * 4;
      int grow = row0 + rr; if (grow > NN - 1) grow = NN - 1;
      const float4 v = *(const float4*)&Ag[(size_t)grow * DD + k0 + cc];
      As[rr][cc] = v.x; As[rr][cc + 1] = v.y; As[rr][cc + 2] = v.z; As[rr][cc + 3] = v.w;
    }
#pragma unroll
    for (int p = 0; p < 4; ++p) {
      int rr = (tid >> 5) + p * 8;
      int cc = (tid & 31) * 4;
      *(float4*)&Ws[rr][cc] = *(const float4*)&Wg[(size_t)(k0 + rr) * DD + cc];
    }
    __syncthreads();
#pragma unroll
    for (int k = 0; k < 32; ++k) {
      float a[4], w[8];
#pragma unroll
      for (int i = 0; i < 4; ++i) a[i] = As[ty * 4 + i][k];
#pragma unroll
      for (int j = 0; j < 8; ++j) w[j] = Ws[k][tx * 8 + j];
#pragma unroll
      for (int i = 0; i < 4; ++i)
#pragma unroll
        for (int j = 0; j < 8; ++j)
          acc[i][j] = fmaf(a[i], w[j], acc[i][j]);
    }
    __syncthreads();
  }
#pragma unroll
  for (int i = 0; i < 4; ++i) {
    int grow = row0 + ty * 4 + i;
    if (grow >= NN) continue;
    float sc = rs_in[r * NN + grow];
    float o[8];
#pragma unroll
    for (int j = 0; j < 8; ++j) o[j] = acc[i][j] * sc + bias[r * DD + tx * 8 + j];
    float4* cp = (float4*)&C[((size_t)r * NN + grow) * DD + tx * 8];
    cp[0] = make_float4(o[0], o[1], o[2], o[3]);
    cp[1] = make_float4(o[4], o[5], o[6], o[7]);
  }
}

// ---------------- score GEMM: score[r,i] = sum_j tanh((rel @ Wa1)[j] + ba1[j]) * wa2[j] --
__global__ __launch_bounds__(256) void score_kernel(const float* __restrict__ A,
                                                    const float* __restrict__ Wa1,
                                                    const float* __restrict__ ba1,
                                                    const float* __restrict__ wa2,
                                                    float* __restrict__ score) {
  const int r = blockIdx.y;
  const int row0 = blockIdx.x * 64;
  __shared__ float As[64][33];
  __shared__ float Ws[32][128];
  const int tid = threadIdx.x;
  const int tx = tid & 15, ty = tid >> 4;
  float acc[4][8] = {};
  const float* Ag = A + (size_t)r * NN * DD;
  for (int k0 = 0; k0 < DD; k0 += 32) {
#pragma unroll
    for (int p = 0; p < 2; ++p) {
      int rr = (tid >> 3) + p * 32;
      int cc = (tid & 7) * 4;
      int grow = row0 + rr; if (grow > NN - 1) grow = NN - 1;
      const float4 v = *(const float4*)&Ag[(size_t)grow * DD + k0 + cc];
      As[rr][cc] = v.x; As[rr][cc + 1] = v.y; As[rr][cc + 2] = v.z; As[rr][cc + 3] = v.w;
    }
#pragma unroll
    for (int p = 0; p < 4; ++p) {
      int rr = (tid >> 5) + p * 8;
      int cc = (tid & 31) * 4;
      *(float4*)&Ws[rr][cc] = *(const float4*)&Wa1[(size_t)(k0 + rr) * DD + cc];
    }
    __syncthreads();
#pragma unroll
    for (int k = 0; k < 32; ++k) {
      float a[4], w[8];
#pragma unroll
      for (int i = 0; i < 4; ++i) a[i] = As[ty * 4 + i][k];
#pragma unroll
      for (int j = 0; j < 8; ++j) w[j] = Ws[k][tx * 8 + j];
#pragma unroll
      for (int i = 0; i < 4; ++i)
#pragma unroll
        for (int j = 0; j < 8; ++j)
          acc[i][j] = fmaf(a[i], w[j], acc[i][j]);
    }
    __syncthreads();
  }
#pragma unroll
  for (int i = 0; i < 4; ++i) {
    float p = 0.f;
#pragma unroll
    for (int j = 0; j < 8; ++j) {
      int c = tx * 8 + j;
      p += tanhf(acc[i][j] + ba1[c]) * wa2[c];
    }
    p += __shfl_xor(p, 1);
    p += __shfl_xor(p, 2);
    p += __shfl_xor(p, 4);
    p += __shfl_xor(p, 8);
    if (tx == 0) {
      int grow = row0 + ty * 4 + i;
      if (grow < NN) score[r * NN + grow] = p;
    }
  }
}

// ---------------- final: softmax over relations + weighted sum -------------------------
__global__ __launch_bounds__(256) void final_kernel(const float* __restrict__ rel,
                                                    const float* __restrict__ score,
                                                    float* __restrict__ out) {
  const int lane = threadIdx.x & 31;
  const int slot = threadIdx.x >> 5;
  int i = blockIdx.x * 8 + slot;
  if (i >= NN) return;
  float s0 = score[i], s1 = score[NN + i], s2 = score[2 * NN + i];
  float m = fmaxf(s0, fmaxf(s1, s2));
  float e0 = __expf(s0 - m), e1 = __expf(s1 - m), e2 = __expf(s2 - m);
  float inv = 1.f / (e0 + e1 + e2);
  e0 *= inv; e1 *= inv; e2 *= inv;
  size_t off = (size_t)i * DD + lane * 4;
  float4 v0 = *(const float4*)&rel[off];
  float4 v1 = *(const float4*)&rel[(size_t)NN * DD + off];
  float4 v2 = *(const float4*)&rel[2 * (size_t)NN * DD + off];
  float4 o;
  o.x = v0.x * e0 + v1.x * e1 + v2.x * e2;
  o.y = v0.y * e0 + v1.y * e1 + v2.y * e2;
  o.z = v0.z * e0 + v1.z * e1 + v2.z * e2;
  o.w = v0.w * e0 + v1.w * e1 + v2.w * e2;
  *(float4*)&out[off] = o;
}

extern "C" void kernel_launch(void* const* d_in, const int* in_sizes, int n_in,
                              void* d_out, int out_size, void* d_ws, size_t ws_size,
                              hipStream_t stream) {
  const float* x   = (const float*)d_in[0];
  const int*   src = (const int*)d_in[1];
  const int*   dst = (const int*)d_in[2];
  const float* W   = (const float*)d_in[3];
  const float* b   = (const float*)d_in[4];
  const float* Wa1 = (const float*)d_in[5];
  const float* ba1 = (const float*)d_in[6];
  const float* wa2 = (const float*)d_in[7];
  float* out = (float*)d_out;

  char* ws = (char*)d_ws;
  size_t off = 0;
  float* agg = (float*)(ws + off); off += (size_t)NSEG * DD * 4;      // 153.6 MB
  int* cnt_out = (int*)(ws + off); off += (size_t)NSEG * 4;
  int* cnt_in  = (int*)(ws + off); off += (size_t)NSEG * 4;
  float* rs_out = (float*)(ws + off); off += (size_t)NSEG * 4;
  float* rs_in  = (float*)(ws + off); off += (size_t)NSEG * 4;
  float* score  = (float*)(ws + off); off += (size_t)NSEG * 4;
  int* offs    = (int*)(ws + off); off += (size_t)(NSEG + 1) * 4;
  int* cursor  = (int*)(ws + off); off += (size_t)NSEG * 4;
  int* blksum  = (int*)(ws + off); off += (size_t)512 * 4;
  int* esrc    = (int*)(ws + off); off += (size_t)NR * NE * 4;        // 7.68 MB
  if (ws_size < off) return;  // fail loudly (output stays poisoned)

  hipMemsetAsync(cnt_out, 0, (size_t)NSEG * 4 * 2, stream);  // cnt_out + cnt_in

  degree_kernel<<<(NR * NE + 255) / 256, 256, 0, stream>>>(src, dst, cnt_out, cnt_in);
  rs_kernel<<<(NSEG + 255) / 256, 256, 0, stream>>>(cnt_out, cnt_in, rs_out, rs_in);
  scan1_kernel<<<NBLK, 256, 0, stream>>>(cnt_in, offs, blksum);
  scan2_kernel<<<1, 512, 0, stream>>>(blksum, NBLK);
  scan3_kernel<<<(NSEG + 255) / 256, 256, 0, stream>>>(offs, blksum, cursor);
  fill_kernel<<<(NR * NE + 255) / 256, 256, 0, stream>>>(src, dst, cursor, esrc);
  aggregate_kernel<<<(NSEG + 3) / 4, 256, 0, stream>>>(x, esrc, offs, rs_out, agg);
  dim3 g1((NN + 63) / 64, NR);
  gemm_rel_kernel<<<g1, 256, 0, stream>>>(agg, W, rs_in, b, agg);
  score_kernel<<<g1, 256, 0, stream>>>(agg, Wa1, ba1, wa2, score);
  final_kernel<<<NN / 8, 256, 0, stream>>>(agg, score, out);
}

// Round 3
// 784.366 us; speedup vs baseline: 4.7156x; 1.0599x over previous
//
#include <hip/hip_runtime.h>

#define NN 100000
#define NE 640000
#define NR 3
#define DD 128
#define NSEG (NR * NN)            // 300000 segments (relation, node)
#define SCAN_BLK 1024             // elements per scan block
#define NBLK ((NSEG + SCAN_BLK - 1) / SCAN_BLK)   // 293

typedef unsigned int u32;

__device__ __forceinline__ u32 bfr(float f) {          // f32 -> bf16 bits (RNE)
  u32 u = __float_as_uint(f);
  return (u + 0x7fffu + ((u >> 16) & 1u)) >> 16;
}
__device__ __forceinline__ u32 packbf(float a, float b) {
  return bfr(a) | (bfr(b) << 16);
}
__device__ __forceinline__ float lo16(u32 u) { return __uint_as_float(u << 16); }
__device__ __forceinline__ float hi16(u32 u) { return __uint_as_float(u & 0xffff0000u); }

// ---------------- x -> packed bf16 ----------------
__global__ __launch_bounds__(256) void convert_x_kernel(const float* __restrict__ x,
                                                        u32* __restrict__ xb) {
  int i = blockIdx.x * 256 + threadIdx.x;
  if (i >= NN * 64) return;
  float2 v = ((const float2*)x)[i];
  xb[i] = packbf(v.x, v.y);
}

// ---------------- degree counting ----------------
__global__ __launch_bounds__(256) void degree_kernel(const int* __restrict__ src,
                                                     const int* __restrict__ dst,
                                                     int* __restrict__ cnt_out,
                                                     int* __restrict__ cnt_in) {
  int i = blockIdx.x * 256 + threadIdx.x;
  if (i >= NR * NE) return;
  int r = i / NE;
  atomicAdd(&cnt_out[r * NN + src[i]], 1);
  atomicAdd(&cnt_in[r * NN + dst[i]], 1);
}

__global__ __launch_bounds__(256) void rs_kernel(const int* __restrict__ cnt_out,
                                                 const int* __restrict__ cnt_in,
                                                 float* __restrict__ rs_out,
                                                 float* __restrict__ rs_in) {
  int i = blockIdx.x * 256 + threadIdx.x;
  if (i >= NSEG) return;
  int co = cnt_out[i]; if (co < 1) co = 1;
  int ci = cnt_in[i]; if (ci < 1) ci = 1;
  rs_out[i] = rsqrtf((float)co);
  rs_in[i]  = rsqrtf((float)ci);
}

// ---------------- counting-sort scan (3 kernels) ----------------
__global__ __launch_bounds__(256) void scan1_kernel(const int* __restrict__ cnt,
                                                    int* __restrict__ offs,
                                                    int* __restrict__ blksum) {
  __shared__ int s[256];
  const int t = threadIdx.x;
  const int base = blockIdx.x * SCAN_BLK + t * 4;
  int v[4] = {0, 0, 0, 0};
#pragma unroll
  for (int j = 0; j < 4; ++j) { int i = base + j; if (i < NSEG) v[j] = cnt[i]; }
  const int tot = v[0] + v[1] + v[2] + v[3];
  s[t] = tot;
  __syncthreads();
  for (int d = 1; d < 256; d <<= 1) {
    int a = (t >= d) ? s[t - d] : 0;
    __syncthreads();
    s[t] += a;
    __syncthreads();
  }
  if (t == 255) blksum[blockIdx.x] = s[255];
  int run = s[t] - tot;  // exclusive prefix within block
#pragma unroll
  for (int j = 0; j < 4; ++j) {
    int i = base + j;
    if (i < NSEG) { offs[i] = run; run += v[j]; }
  }
}

__global__ __launch_bounds__(512) void scan2_kernel(int* __restrict__ blksum, int n) {
  __shared__ int s[512];
  const int t = threadIdx.x;
  int v = (t < n) ? blksum[t] : 0;
  s[t] = v;
  __syncthreads();
  for (int d = 1; d < 512; d <<= 1) {
    int a = (t >= d) ? s[t - d] : 0;
    __syncthreads();
    s[t] += a;
    __syncthreads();
  }
  if (t < n) blksum[t] = s[t] - v;  // exclusive
}

__global__ __launch_bounds__(256) void scan3_kernel(int* __restrict__ offs,
                                                    const int* __restrict__ blksum,
                                                    int* __restrict__ cursor) {
  int i = blockIdx.x * 256 + threadIdx.x;
  if (i < NSEG) {
    int o = offs[i] + blksum[i >> 10];
    offs[i] = o;
    cursor[i] = o;
  }
  if (i == 0) offs[NSEG] = NR * NE;
}

// ---------------- fill dst-sorted edge list ----------------
__global__ __launch_bounds__(256) void fill_kernel(const int* __restrict__ src,
                                                   const int* __restrict__ dst,
                                                   int* __restrict__ cursor,
                                                   int* __restrict__ esrc) {
  int i = blockIdx.x * 256 + threadIdx.x;
  if (i >= NR * NE) return;
  int r = i / NE;
  int seg = r * NN + dst[i];
  int pos = atomicAdd(&cursor[seg], 1);
  esrc[pos] = src[i];
}

// ---------------- gather aggregate (bf16 x, f32 accum, bf16 out) ----------------
__global__ __launch_bounds__(256) void aggregate_kernel(const u32* __restrict__ xb,
                                                        const int* __restrict__ esrc,
                                                        const int* __restrict__ offs,
                                                        const float* __restrict__ rs_out,
                                                        u32* __restrict__ aggb) {
  const int lane = threadIdx.x & 63;
  const int w = threadIdx.x >> 6;
  const int seg = blockIdx.x * 4 + w;
  if (seg >= NSEG) return;
  const int r = seg / NN;
  const int beg = offs[seg], end = offs[seg + 1];
  const float* rs = rs_out + r * NN;
  float a0 = 0.f, a1 = 0.f;
  int e = beg;
  for (; e + 1 < end; e += 2) {
    int s0 = esrc[e], s1 = esrc[e + 1];
    float c0 = rs[s0], c1 = rs[s1];
    u32 u0 = xb[(size_t)s0 * 64 + lane];
    u32 u1 = xb[(size_t)s1 * 64 + lane];
    a0 = fmaf(lo16(u0), c0, a0);
    a1 = fmaf(hi16(u0), c0, a1);
    a0 = fmaf(lo16(u1), c1, a0);
    a1 = fmaf(hi16(u1), c1, a1);
  }
  if (e < end) {
    int s0 = esrc[e];
    float c0 = rs[s0];
    u32 u0 = xb[(size_t)s0 * 64 + lane];
    a0 = fmaf(lo16(u0), c0, a0);
    a1 = fmaf(hi16(u0), c0, a1);
  }
  aggb[(size_t)seg * 64 + lane] = packbf(a0, a1);
}

// ---------------- fused tail: rel GEMM + attention score + softmax combine ------------
__device__ __forceinline__ void stage_w(const float* __restrict__ Wg, int k0,
                                        float (&Wst)[32][132], int tid) {
#pragma unroll
  for (int p = 0; p < 4; ++p) {
    int idx = tid + p * 256;
    int kr = idx >> 5;
    int cc = (idx & 31) * 4;
    *(float4*)&Wst[kr][cc] = *(const float4*)&Wg[(size_t)(k0 + kr) * DD + cc];
  }
}

__device__ __forceinline__ void gemm_slab(const u32* A, int astride, int acol0,
                                          const float (&Wst)[32][132],
                                          int tx, int ty, float (&acc)[4][8]) {
#pragma unroll 4
  for (int kk = 0; kk < 16; ++kk) {
    const float4 w0a = *(const float4*)&Wst[2 * kk][tx * 4];
    const float4 w0b = *(const float4*)&Wst[2 * kk][tx * 4 + 64];
    const float4 w1a = *(const float4*)&Wst[2 * kk + 1][tx * 4];
    const float4 w1b = *(const float4*)&Wst[2 * kk + 1][tx * 4 + 64];
#pragma unroll
    for (int i = 0; i < 4; ++i) {
      const u32 u = A[(ty * 4 + i) * astride + acol0 + kk];
      const float a0 = lo16(u);
      const float a1 = hi16(u);
      acc[i][0] = fmaf(a0, w0a.x, acc[i][0]);
      acc[i][1] = fmaf(a0, w0a.y, acc[i][1]);
      acc[i][2] = fmaf(a0, w0a.z, acc[i][2]);
      acc[i][3] = fmaf(a0, w0a.w, acc[i][3]);
      acc[i][4] = fmaf(a0, w0b.x, acc[i][4]);
      acc[i][5] = fmaf(a0, w0b.y, acc[i][5]);
      acc[i][6] = fmaf(a0, w0b.z, acc[i][6]);
      acc[i][7] = fmaf(a0, w0b.w, acc[i][7]);
      acc[i][0] = fmaf(a1, w1a.x, acc[i][0]);
      acc[i][1] = fmaf(a1, w1a.y, acc[i][1]);
      acc[i][2] = fmaf(a1, w1a.z, acc[i][2]);
      acc[i][3] = fmaf(a1, w1a.w, acc[i][3]);
      acc[i][4] = fmaf(a1, w1b.x, acc[i][4]);
      acc[i][5] = fmaf(a1, w1b.y, acc[i][5]);
      acc[i][6] = fmaf(a1, w1b.z, acc[i][6]);
      acc[i][7] = fmaf(a1, w1b.w, acc[i][7]);
    }
  }
}

__global__ __launch_bounds__(256, 2) void fused_tail_kernel(
    const u32* __restrict__ aggb, const float* __restrict__ Wmat,
    const float* __restrict__ rs_in, const float* __restrict__ bias,
    const float* __restrict__ Wa1, const float* __restrict__ ba1,
    const float* __restrict__ wa2, float* __restrict__ out) {
  __shared__ u32 AsB[64][20];
  __shared__ float Wst[32][132];
  __shared__ u32 relbf[3][64][65];
  __shared__ float scoreS[3][64];

  const int tid = threadIdx.x;
  const int tx = tid & 15, ty = tid >> 4;
  const int row0 = blockIdx.x * 64;

  float acc[3][4][8];
#pragma unroll
  for (int r = 0; r < 3; ++r)
#pragma unroll
    for (int i = 0; i < 4; ++i)
#pragma unroll
      for (int j = 0; j < 8; ++j) acc[r][i][j] = 0.f;

  // -------- phase 1: rel_r = (agg_r @ W_r) * rs_in + b_r (f32 accum, bf16 inputs) ----
#pragma unroll
  for (int r = 0; r < 3; ++r) {
    const u32* Ag = aggb + (size_t)r * NN * 64;
    const float* Wg = Wmat + (size_t)r * DD * DD;
    for (int s4 = 0; s4 < 4; ++s4) {
      __syncthreads();
      {
        const int arow = tid >> 2, ac = tid & 3;
        int grow = row0 + arow; if (grow > NN - 1) grow = NN - 1;
        *(uint4*)&AsB[arow][ac * 4] =
            *(const uint4*)&Ag[(size_t)grow * 64 + s4 * 16 + ac * 4];
      }
      stage_w(Wg, s4 * 32, Wst, tid);
      __syncthreads();
      gemm_slab(&AsB[0][0], 20, 0, Wst, tx, ty, acc[r]);
    }
    // epilogue: scale + bias, write bf16 rel copy into LDS for the score GEMM
#pragma unroll
    for (int i = 0; i < 4; ++i) {
      int grow = row0 + ty * 4 + i;
      int gc = grow > NN - 1 ? NN - 1 : grow;
      float sc = rs_in[r * NN + gc];
#pragma unroll
      for (int j = 0; j < 8; ++j) {
        int col = (j < 4) ? (tx * 4 + j) : (64 + tx * 4 + j - 4);
        acc[r][i][j] = fmaf(acc[r][i][j], sc, bias[r * DD + col]);
      }
      int lrow = ty * 4 + i;
      relbf[r][lrow][tx * 2]          = packbf(acc[r][i][0], acc[r][i][1]);
      relbf[r][lrow][tx * 2 + 1]      = packbf(acc[r][i][2], acc[r][i][3]);
      relbf[r][lrow][32 + tx * 2]     = packbf(acc[r][i][4], acc[r][i][5]);
      relbf[r][lrow][32 + tx * 2 + 1] = packbf(acc[r][i][6], acc[r][i][7]);
    }
  }

  // -------- phase 2: score[r] = sum_c tanh(rel_r @ Wa1 + ba1)_c * wa2_c --------------
#pragma unroll
  for (int r = 0; r < 3; ++r) {
    float t[4][8];
#pragma unroll
    for (int i = 0; i < 4; ++i)
#pragma unroll
      for (int j = 0; j < 8; ++j) t[i][j] = 0.f;
    for (int s4 = 0; s4 < 4; ++s4) {
      __syncthreads();
      stage_w(Wa1, s4 * 32, Wst, tid);
      __syncthreads();
      gemm_slab(&relbf[r][0][0], 65, s4 * 16, Wst, tx, ty, t);
    }
#pragma unroll
    for (int i = 0; i < 4; ++i) {
      float p = 0.f;
#pragma unroll
      for (int j = 0; j < 8; ++j) {
        int col = (j < 4) ? (tx * 4 + j) : (64 + tx * 4 + j - 4);
        p += tanhf(t[i][j] + ba1[col]) * wa2[col];
      }
      p += __shfl_xor(p, 1);
      p += __shfl_xor(p, 2);
      p += __shfl_xor(p, 4);
      p += __shfl_xor(p, 8);
      if (tx == 0) scoreS[r][ty * 4 + i] = p;
    }
  }

  __syncthreads();

  // -------- phase 3: softmax over relations, weighted combine from registers --------
#pragma unroll
  for (int i = 0; i < 4; ++i) {
    int grow = row0 + ty * 4 + i;
    if (grow >= NN) continue;
    int lrow = ty * 4 + i;
    float s0 = scoreS[0][lrow], s1 = scoreS[1][lrow], s2 = scoreS[2][lrow];
    float m = fmaxf(s0, fmaxf(s1, s2));
    float e0 = expf(s0 - m), e1 = expf(s1 - m), e2 = expf(s2 - m);
    float inv = 1.f / (e0 + e1 + e2);
    e0 *= inv; e1 *= inv; e2 *= inv;
    float o[8];
#pragma unroll
    for (int j = 0; j < 8; ++j)
      o[j] = acc[0][i][j] * e0 + acc[1][i][j] * e1 + acc[2][i][j] * e2;
    *(float4*)&out[(size_t)grow * DD + tx * 4] = make_float4(o[0], o[1], o[2], o[3]);
    *(float4*)&out[(size_t)grow * DD + 64 + tx * 4] = make_float4(o[4], o[5], o[6], o[7]);
  }
}

extern "C" void kernel_launch(void* const* d_in, const int* in_sizes, int n_in,
                              void* d_out, int out_size, void* d_ws, size_t ws_size,
                              hipStream_t stream) {
  const float* x   = (const float*)d_in[0];
  const int*   src = (const int*)d_in[1];
  const int*   dst = (const int*)d_in[2];
  const float* W   = (const float*)d_in[3];
  const float* b   = (const float*)d_in[4];
  const float* Wa1 = (const float*)d_in[5];
  const float* ba1 = (const float*)d_in[6];
  const float* wa2 = (const float*)d_in[7];
  float* out = (float*)d_out;

  char* ws = (char*)d_ws;
  size_t off = 0;
  u32* aggb = (u32*)(ws + off); off += (size_t)NSEG * 64 * 4;   // 76.8 MB
  u32* xb   = (u32*)(ws + off); off += (size_t)NN * 64 * 4;     // 25.6 MB
  int* cnt_out = (int*)(ws + off); off += (size_t)NSEG * 4;
  int* cnt_in  = (int*)(ws + off); off += (size_t)NSEG * 4;
  float* rs_out = (float*)(ws + off); off += (size_t)NSEG * 4;
  float* rs_in  = (float*)(ws + off); off += (size_t)NSEG * 4;
  int* offs    = (int*)(ws + off); off += (size_t)(NSEG + 4) * 4;
  int* cursor  = (int*)(ws + off); off += (size_t)NSEG * 4;
  int* blksum  = (int*)(ws + off); off += (size_t)512 * 4;
  int* esrc    = (int*)(ws + off); off += (size_t)NR * NE * 4;  // 7.68 MB
  if (ws_size < off) return;  // fail loudly (output stays poisoned)

  hipMemsetAsync(cnt_out, 0, (size_t)NSEG * 4 * 2, stream);  // cnt_out + cnt_in

  convert_x_kernel<<<(NN * 64 + 255) / 256, 256, 0, stream>>>(x, xb);
  degree_kernel<<<(NR * NE + 255) / 256, 256, 0, stream>>>(src, dst, cnt_out, cnt_in);
  rs_kernel<<<(NSEG + 255) / 256, 256, 0, stream>>>(cnt_out, cnt_in, rs_out, rs_in);
  scan1_kernel<<<NBLK, 256, 0, stream>>>(cnt_in, offs, blksum);
  scan2_kernel<<<1, 512, 0, stream>>>(blksum, NBLK);
  scan3_kernel<<<(NSEG + 255) / 256, 256, 0, stream>>>(offs, blksum, cursor);
  fill_kernel<<<(NR * NE + 255) / 256, 256, 0, stream>>>(src, dst, cursor, esrc);
  aggregate_kernel<<<(NSEG + 3) / 4, 256, 0, stream>>>(xb, esrc, offs, rs_out, aggb);
  fused_tail_kernel<<<(NN + 63) / 64, 256, 0, stream>>>(aggb, W, rs_in, b, Wa1, ba1,
                                                        wa2, out);
}

// Round 4
// 669.974 us; speedup vs baseline: 5.5207x; 1.1707x over previous
//
#include <hip/hip_runtime.h>

#define NN 100000
#define NE 640000
#define NR 3
#define DD 128
#define NSEG (NR * NN)            // 300000 segments (relation, node)
#define SCAN_BLK 1024             // elements per scan block
#define NBLK ((NSEG + SCAN_BLK - 1) / SCAN_BLK)   // 293

typedef unsigned int u32;
typedef short bf8_t __attribute__((ext_vector_type(8)));   // 8 bf16 (4 VGPRs)
typedef float f4_t __attribute__((ext_vector_type(4)));

union U4 { uint4 u; bf8_t b; };

__device__ __forceinline__ u32 bfr(float f) {          // f32 -> bf16 bits (RNE)
  u32 u = __float_as_uint(f);
  return (u + 0x7fffu + ((u >> 16) & 1u)) >> 16;
}
__device__ __forceinline__ u32 packbf(float a, float b) {
  return bfr(a) | (bfr(b) << 16);
}
__device__ __forceinline__ float lo16(u32 u) { return __uint_as_float(u << 16); }
__device__ __forceinline__ float hi16(u32 u) { return __uint_as_float(u & 0xffff0000u); }
__device__ __forceinline__ float bf2f(u32 bits) { return __uint_as_float(bits << 16); }

__device__ __forceinline__ bf8_t ldfrag(const u32* p) {
  U4 t; t.u = *(const uint4*)p; return t.b;
}

// ---------------- x -> packed bf16 ----------------
__global__ __launch_bounds__(256) void convert_x_kernel(const float* __restrict__ x,
                                                        u32* __restrict__ xb) {
  int i = blockIdx.x * 256 + threadIdx.x;
  if (i >= NN * 64) return;
  float2 v = ((const float2*)x)[i];
  xb[i] = packbf(v.x, v.y);
}

// ---------------- degree counting ----------------
__global__ __launch_bounds__(256) void degree_kernel(const int* __restrict__ src,
                                                     const int* __restrict__ dst,
                                                     int* __restrict__ cnt_out,
                                                     int* __restrict__ cnt_in) {
  int i = blockIdx.x * 256 + threadIdx.x;
  if (i >= NR * NE) return;
  int r = i / NE;
  atomicAdd(&cnt_out[r * NN + src[i]], 1);
  atomicAdd(&cnt_in[r * NN + dst[i]], 1);
}

__global__ __launch_bounds__(256) void rs_kernel(const int* __restrict__ cnt_out,
                                                 const int* __restrict__ cnt_in,
                                                 float* __restrict__ rs_out,
                                                 float* __restrict__ rs_in) {
  int i = blockIdx.x * 256 + threadIdx.x;
  if (i >= NSEG) return;
  int co = cnt_out[i]; if (co < 1) co = 1;
  int ci = cnt_in[i]; if (ci < 1) ci = 1;
  rs_out[i] = rsqrtf((float)co);
  rs_in[i]  = rsqrtf((float)ci);
}

// ---------------- counting-sort scan (3 kernels) ----------------
__global__ __launch_bounds__(256) void scan1_kernel(const int* __restrict__ cnt,
                                                    int* __restrict__ offs,
                                                    int* __restrict__ blksum) {
  __shared__ int s[256];
  const int t = threadIdx.x;
  const int base = blockIdx.x * SCAN_BLK + t * 4;
  int v[4] = {0, 0, 0, 0};
#pragma unroll
  for (int j = 0; j < 4; ++j) { int i = base + j; if (i < NSEG) v[j] = cnt[i]; }
  const int tot = v[0] + v[1] + v[2] + v[3];
  s[t] = tot;
  __syncthreads();
  for (int d = 1; d < 256; d <<= 1) {
    int a = (t >= d) ? s[t - d] : 0;
    __syncthreads();
    s[t] += a;
    __syncthreads();
  }
  if (t == 255) blksum[blockIdx.x] = s[255];
  int run = s[t] - tot;  // exclusive prefix within block
#pragma unroll
  for (int j = 0; j < 4; ++j) {
    int i = base + j;
    if (i < NSEG) { offs[i] = run; run += v[j]; }
  }
}

__global__ __launch_bounds__(512) void scan2_kernel(int* __restrict__ blksum, int n) {
  __shared__ int s[512];
  const int t = threadIdx.x;
  int v = (t < n) ? blksum[t] : 0;
  s[t] = v;
  __syncthreads();
  for (int d = 1; d < 512; d <<= 1) {
    int a = (t >= d) ? s[t - d] : 0;
    __syncthreads();
    s[t] += a;
    __syncthreads();
  }
  if (t < n) blksum[t] = s[t] - v;  // exclusive
}

__global__ __launch_bounds__(256) void scan3_kernel(int* __restrict__ offs,
                                                    const int* __restrict__ blksum,
                                                    int* __restrict__ cursor) {
  int i = blockIdx.x * 256 + threadIdx.x;
  if (i < NSEG) {
    int o = offs[i] + blksum[i >> 10];
    offs[i] = o;
    cursor[i] = o;
  }
  if (i == 0) offs[NSEG] = NR * NE;
}

// ---------------- fill dst-sorted edge list ----------------
__global__ __launch_bounds__(256) void fill_kernel(const int* __restrict__ src,
                                                   const int* __restrict__ dst,
                                                   int* __restrict__ cursor,
                                                   int* __restrict__ esrc) {
  int i = blockIdx.x * 256 + threadIdx.x;
  if (i >= NR * NE) return;
  int r = i / NE;
  int seg = r * NN + dst[i];
  int pos = atomicAdd(&cursor[seg], 1);
  esrc[pos] = src[i];
}

// ---------------- gather aggregate (bf16 x, f32 accum, bf16 out) ----------------
__global__ __launch_bounds__(256) void aggregate_kernel(const u32* __restrict__ xb,
                                                        const int* __restrict__ esrc,
                                                        const int* __restrict__ offs,
                                                        const float* __restrict__ rs_out,
                                                        u32* __restrict__ aggb) {
  const int lane = threadIdx.x & 63;
  const int w = threadIdx.x >> 6;
  const int seg = blockIdx.x * 4 + w;
  if (seg >= NSEG) return;
  const int r = seg / NN;
  const int beg = offs[seg], end = offs[seg + 1];
  const float* rs = rs_out + r * NN;
  float a0 = 0.f, a1 = 0.f;
  int e = beg;
  for (; e + 1 < end; e += 2) {
    int s0 = esrc[e], s1 = esrc[e + 1];
    float c0 = rs[s0], c1 = rs[s1];
    u32 u0 = xb[(size_t)s0 * 64 + lane];
    u32 u1 = xb[(size_t)s1 * 64 + lane];
    a0 = fmaf(lo16(u0), c0, a0);
    a1 = fmaf(hi16(u0), c0, a1);
    a0 = fmaf(lo16(u1), c1, a0);
    a1 = fmaf(hi16(u1), c1, a1);
  }
  if (e < end) {
    int s0 = esrc[e];
    float c0 = rs[s0];
    u32 u0 = xb[(size_t)s0 * 64 + lane];
    a0 = fmaf(lo16(u0), c0, a0);
    a1 = fmaf(hi16(u0), c0, a1);
  }
  aggb[(size_t)seg * 64 + lane] = packbf(a0, a1);
}

// ---------------- prep 1: WWa1[r] = W[r] @ Wa1 (f32) ----------------
__global__ __launch_bounds__(256) void prep_wwa1_kernel(const float* __restrict__ W,
                                                        const float* __restrict__ Wa1,
                                                        float* __restrict__ WWa1) {
  int idx = blockIdx.x * 256 + threadIdx.x;       // r*16384 + i*128 + c
  if (idx >= NR * DD * DD) return;
  int r = idx >> 14, rem = idx & 16383, i = rem >> 7, c = rem & 127;
  const float* wrow = W + (r << 14) + (i << 7);
  float s = 0.f;
#pragma unroll 8
  for (int k = 0; k < DD; ++k) s = fmaf(wrow[k], Wa1[k * DD + c], s);
  WWa1[idx] = s;
}

// ---------------- prep 2: transpose + bf16 hi/lo split, fragment-ready -----------------
// wt[n][ku32]: bf16-pair rows along k (64 u32 per row of 128 k)
__global__ __launch_bounds__(256) void prep_pack_kernel(const float* __restrict__ W,
                                                        const float* __restrict__ WWa1,
                                                        u32* __restrict__ wt_hi,
                                                        u32* __restrict__ wt_lo,
                                                        u32* __restrict__ wwt_hi,
                                                        u32* __restrict__ wwt_lo) {
  int idx = blockIdx.x * 256 + threadIdx.x;       // r*8192 + n*64 + ku
  if (idx >= NR * DD * 64) return;
  int r = idx >> 13, rem = idx & 8191, n = rem >> 6, ku = rem & 63;
  int k0 = ku * 2;
  {
    const float* M = W + (r << 14);
    float w0 = M[k0 * DD + n], w1 = M[(k0 + 1) * DD + n];
    u32 h0 = bfr(w0), h1 = bfr(w1);
    float l0 = w0 - bf2f(h0), l1 = w1 - bf2f(h1);
    wt_hi[idx] = h0 | (h1 << 16);
    wt_lo[idx] = packbf(l0, l1);
  }
  {
    const float* M = WWa1 + (r << 14);
    float w0 = M[k0 * DD + n], w1 = M[(k0 + 1) * DD + n];
    u32 h0 = bfr(w0), h1 = bfr(w1);
    float l0 = w0 - bf2f(h0), l1 = w1 - bf2f(h1);
    wwt_hi[idx] = h0 | (h1 << 16);
    wwt_lo[idx] = packbf(l0, l1);
  }
}

// ---------------- prep 3: bsum[r][c] = (b_r @ Wa1)[c] + ba1[c] ----------------
__global__ __launch_bounds__(256) void prep_bsum_kernel(const float* __restrict__ b,
                                                        const float* __restrict__ Wa1,
                                                        const float* __restrict__ ba1,
                                                        float* __restrict__ bsum) {
  int idx = blockIdx.x * 256 + threadIdx.x;       // r*128 + c
  if (idx >= NR * DD) return;
  int r = idx >> 7, c = idx & 127;
  float s = ba1[c];
#pragma unroll 8
  for (int k = 0; k < DD; ++k) s = fmaf(b[r * DD + k], Wa1[k * DD + c], s);
  bsum[idx] = s;
}

// ---------------- fused tail (MFMA): rel GEMM + score GEMM + softmax combine ----------
#define MFMA(a, b, c) __builtin_amdgcn_mfma_f32_16x16x32_bf16((a), (b), (c), 0, 0, 0)

__global__ __launch_bounds__(256, 2) void tail_mfma_kernel(
    const u32* __restrict__ aggb,
    const u32* __restrict__ wt_hi, const u32* __restrict__ wt_lo,
    const u32* __restrict__ wwt_hi, const u32* __restrict__ wwt_lo,
    const float* __restrict__ rs_in, const float* __restrict__ bias,
    const float* __restrict__ bsum, const float* __restrict__ wa2,
    float* __restrict__ out) {
  __shared__ float scoreS[NR][2][64];
  const int tid = threadIdx.x;
  const int l = tid & 63;
  const int w = tid >> 6;
  const int wr = w >> 1, wc = w & 1;
  const int row0 = blockIdx.x * 64;
  const int l15 = l & 15, lg = l >> 4;

  // A fragment rows (for loads) and C fragment row base
  int arow[2];
  arow[0] = min(row0 + wr * 32 + l15, NN - 1);
  arow[1] = min(row0 + wr * 32 + 16 + l15, NN - 1);

  float wa2v[4];
#pragma unroll
  for (int nf = 0; nf < 4; ++nf) wa2v[nf] = wa2[wc * 64 + nf * 16 + l15];

  f4_t rel[NR][2][4];

#pragma unroll
  for (int r = 0; r < NR; ++r) {
    f4_t c1[2][4], c2[2][4];
#pragma unroll
    for (int m = 0; m < 2; ++m)
#pragma unroll
      for (int nf = 0; nf < 4; ++nf) { c1[m][nf] = (f4_t)0.f; c2[m][nf] = (f4_t)0.f; }

#pragma unroll
    for (int ks = 0; ks < 4; ++ks) {
      bf8_t a0 = ldfrag(aggb + ((size_t)r * NN + arow[0]) * 64 + ks * 16 + lg * 4);
      bf8_t a1 = ldfrag(aggb + ((size_t)r * NN + arow[1]) * 64 + ks * 16 + lg * 4);
#pragma unroll
      for (int nf = 0; nf < 4; ++nf) {
        const int n = wc * 64 + nf * 16 + l15;
        const size_t bo = ((size_t)r * DD + n) * 64 + ks * 16 + lg * 4;
        bf8_t bh = ldfrag(wt_hi + bo);
        bf8_t bl = ldfrag(wt_lo + bo);
        bf8_t gh = ldfrag(wwt_hi + bo);
        bf8_t gl = ldfrag(wwt_lo + bo);
        c1[0][nf] = MFMA(a0, bh, c1[0][nf]);
        c1[0][nf] = MFMA(a0, bl, c1[0][nf]);
        c1[1][nf] = MFMA(a1, bh, c1[1][nf]);
        c1[1][nf] = MFMA(a1, bl, c1[1][nf]);
        c2[0][nf] = MFMA(a0, gh, c2[0][nf]);
        c2[0][nf] = MFMA(a0, gl, c2[0][nf]);
        c2[1][nf] = MFMA(a1, gh, c2[1][nf]);
        c2[1][nf] = MFMA(a1, gl, c2[1][nf]);
      }
    }

    // epilogue: rel = c1*rs + b;  score partial from tanh(c2*rs + bsum)*wa2
#pragma unroll
    for (int m = 0; m < 2; ++m) {
      float rsv[4];
#pragma unroll
      for (int reg = 0; reg < 4; ++reg) {
        int crow = row0 + wr * 32 + m * 16 + lg * 4 + reg;
        rsv[reg] = rs_in[r * NN + min(crow, NN - 1)];
      }
      float part[4] = {0.f, 0.f, 0.f, 0.f};
#pragma unroll
      for (int nf = 0; nf < 4; ++nf) {
        int col = wc * 64 + nf * 16 + l15;
        float bv = bias[r * DD + col];
        float bs = bsum[r * DD + col];
#pragma unroll
        for (int reg = 0; reg < 4; ++reg) {
          rel[r][m][nf][reg] = fmaf(c1[m][nf][reg], rsv[reg], bv);
          float t = fmaf(c2[m][nf][reg], rsv[reg], bs);
          t = fminf(fmaxf(t, -15.f), 15.f);
          float ex = __expf(2.f * t);
          float th = (ex - 1.f) / (ex + 1.f);
          part[reg] = fmaf(th, wa2v[nf], part[reg]);
        }
      }
#pragma unroll
      for (int reg = 0; reg < 4; ++reg) {
        float p = part[reg];
        p += __shfl_xor(p, 1);
        p += __shfl_xor(p, 2);
        p += __shfl_xor(p, 4);
        p += __shfl_xor(p, 8);
        if (l15 == 0) scoreS[r][wc][wr * 32 + m * 16 + lg * 4 + reg] = p;
      }
    }
  }
  __syncthreads();

  // softmax over relations + combine from registers
#pragma unroll
  for (int m = 0; m < 2; ++m) {
#pragma unroll
    for (int reg = 0; reg < 4; ++reg) {
      int rib = wr * 32 + m * 16 + lg * 4 + reg;
      int crow = row0 + rib;
      float s0 = scoreS[0][0][rib] + scoreS[0][1][rib];
      float s1 = scoreS[1][0][rib] + scoreS[1][1][rib];
      float s2 = scoreS[2][0][rib] + scoreS[2][1][rib];
      float mx = fmaxf(s0, fmaxf(s1, s2));
      float e0 = __expf(s0 - mx), e1 = __expf(s1 - mx), e2 = __expf(s2 - mx);
      float inv = 1.f / (e0 + e1 + e2);
      e0 *= inv; e1 *= inv; e2 *= inv;
      if (crow < NN) {
#pragma unroll
        for (int nf = 0; nf < 4; ++nf) {
          int col = wc * 64 + nf * 16 + l15;
          out[(size_t)crow * DD + col] =
              rel[0][m][nf][reg] * e0 + rel[1][m][nf][reg] * e1 + rel[2][m][nf][reg] * e2;
        }
      }
    }
  }
}

extern "C" void kernel_launch(void* const* d_in, const int* in_sizes, int n_in,
                              void* d_out, int out_size, void* d_ws, size_t ws_size,
                              hipStream_t stream) {
  const float* x   = (const float*)d_in[0];
  const int*   src = (const int*)d_in[1];
  const int*   dst = (const int*)d_in[2];
  const float* W   = (const float*)d_in[3];
  const float* b   = (const float*)d_in[4];
  const float* Wa1 = (const float*)d_in[5];
  const float* ba1 = (const float*)d_in[6];
  const float* wa2 = (const float*)d_in[7];
  float* out = (float*)d_out;

  char* ws = (char*)d_ws;
  size_t off = 0;
  u32* aggb = (u32*)(ws + off); off += (size_t)NSEG * 64 * 4;   // 76.8 MB
  u32* xb   = (u32*)(ws + off); off += (size_t)NN * 64 * 4;     // 25.6 MB
  int* cnt_out = (int*)(ws + off); off += (size_t)NSEG * 4;
  int* cnt_in  = (int*)(ws + off); off += (size_t)NSEG * 4;
  float* rs_out = (float*)(ws + off); off += (size_t)NSEG * 4;
  float* rs_in  = (float*)(ws + off); off += (size_t)NSEG * 4;
  int* offs    = (int*)(ws + off); off += (size_t)(NSEG + 4) * 4;
  int* cursor  = (int*)(ws + off); off += (size_t)NSEG * 4;
  int* blksum  = (int*)(ws + off); off += (size_t)512 * 4;
  int* esrc    = (int*)(ws + off); off += (size_t)NR * NE * 4;  // 7.68 MB
  float* WWa1  = (float*)(ws + off); off += (size_t)NR * DD * DD * 4;
  u32* wt_hi   = (u32*)(ws + off); off += (size_t)NR * DD * 64 * 4;
  u32* wt_lo   = (u32*)(ws + off); off += (size_t)NR * DD * 64 * 4;
  u32* wwt_hi  = (u32*)(ws + off); off += (size_t)NR * DD * 64 * 4;
  u32* wwt_lo  = (u32*)(ws + off); off += (size_t)NR * DD * 64 * 4;
  float* bsum  = (float*)(ws + off); off += (size_t)NR * DD * 4;
  if (ws_size < off) return;  // fail loudly (output stays poisoned)

  hipMemsetAsync(cnt_out, 0, (size_t)NSEG * 4 * 2, stream);  // cnt_out + cnt_in

  // weight prep (independent of graph chain)
  prep_wwa1_kernel<<<(NR * DD * DD + 255) / 256, 256, 0, stream>>>(W, Wa1, WWa1);
  prep_pack_kernel<<<(NR * DD * 64 + 255) / 256, 256, 0, stream>>>(W, WWa1, wt_hi, wt_lo,
                                                                   wwt_hi, wwt_lo);
  prep_bsum_kernel<<<(NR * DD + 255) / 256, 256, 0, stream>>>(b, Wa1, ba1, bsum);

  convert_x_kernel<<<(NN * 64 + 255) / 256, 256, 0, stream>>>(x, xb);
  degree_kernel<<<(NR * NE + 255) / 256, 256, 0, stream>>>(src, dst, cnt_out, cnt_in);
  rs_kernel<<<(NSEG + 255) / 256, 256, 0, stream>>>(cnt_out, cnt_in, rs_out, rs_in);
  scan1_kernel<<<NBLK, 256, 0, stream>>>(cnt_in, offs, blksum);
  scan2_kernel<<<1, 512, 0, stream>>>(blksum, NBLK);
  scan3_kernel<<<(NSEG + 255) / 256, 256, 0, stream>>>(offs, blksum, cursor);
  fill_kernel<<<(NR * NE + 255) / 256, 256, 0, stream>>>(src, dst, cursor, esrc);
  aggregate_kernel<<<(NSEG + 3) / 4, 256, 0, stream>>>(xb, esrc, offs, rs_out, aggb);
  tail_mfma_kernel<<<(NN + 63) / 64, 256, 0, stream>>>(aggb, wt_hi, wt_lo, wwt_hi, wwt_lo,
                                                       rs_in, b, bsum, wa2, out);
}

// Round 5
// 617.968 us; speedup vs baseline: 5.9853x; 1.0842x over previous
//
#include <hip/hip_runtime.h>

#define NN 100000
#define NE 640000
#define NR 3
#define DD 128
#define NSEG (NR * NN)            // 300000 segments (relation, node)
#define SCAN_BLK 1024             // elements per scan block
#define NBLK ((NSEG + SCAN_BLK - 1) / SCAN_BLK)   // 293

typedef unsigned int u32;
typedef short bf8_t __attribute__((ext_vector_type(8)));   // 8 bf16 (4 VGPRs)
typedef float f4_t __attribute__((ext_vector_type(4)));

union U4 { uint4 u; bf8_t b; };

__device__ __forceinline__ u32 bfr(float f) {          // f32 -> bf16 bits (RNE)
  u32 u = __float_as_uint(f);
  return (u + 0x7fffu + ((u >> 16) & 1u)) >> 16;
}
__device__ __forceinline__ u32 packbf(float a, float b) {
  return bfr(a) | (bfr(b) << 16);
}
__device__ __forceinline__ float lo16(u32 u) { return __uint_as_float(u << 16); }
__device__ __forceinline__ float hi16(u32 u) { return __uint_as_float(u & 0xffff0000u); }
__device__ __forceinline__ float bf2f(u32 bits) { return __uint_as_float(bits << 16); }

__device__ __forceinline__ bf8_t ldfrag(const u32* p) {
  U4 t; t.u = *(const uint4*)p; return t.b;
}

// ---------------- x -> packed bf16 ----------------
__global__ __launch_bounds__(256) void convert_x_kernel(const float* __restrict__ x,
                                                        u32* __restrict__ xb) {
  int i = blockIdx.x * 256 + threadIdx.x;
  if (i >= NN * 64) return;
  float2 v = ((const float2*)x)[i];
  xb[i] = packbf(v.x, v.y);
}

// ---------------- degree counting ----------------
__global__ __launch_bounds__(256) void degree_kernel(const int* __restrict__ src,
                                                     const int* __restrict__ dst,
                                                     int* __restrict__ cnt_out,
                                                     int* __restrict__ cnt_in) {
  int i = blockIdx.x * 256 + threadIdx.x;
  if (i >= NR * NE) return;
  int r = i / NE;
  atomicAdd(&cnt_out[r * NN + src[i]], 1);
  atomicAdd(&cnt_in[r * NN + dst[i]], 1);
}

__global__ __launch_bounds__(256) void rs_kernel(const int* __restrict__ cnt_out,
                                                 const int* __restrict__ cnt_in,
                                                 float* __restrict__ rs_out,
                                                 float* __restrict__ rs_in) {
  int i = blockIdx.x * 256 + threadIdx.x;
  if (i >= NSEG) return;
  int co = cnt_out[i]; if (co < 1) co = 1;
  int ci = cnt_in[i]; if (ci < 1) ci = 1;
  rs_out[i] = rsqrtf((float)co);
  rs_in[i]  = rsqrtf((float)ci);
}

// ---------------- counting-sort scan (3 kernels) ----------------
__global__ __launch_bounds__(256) void scan1_kernel(const int* __restrict__ cnt,
                                                    int* __restrict__ offs,
                                                    int* __restrict__ blksum) {
  __shared__ int s[256];
  const int t = threadIdx.x;
  const int base = blockIdx.x * SCAN_BLK + t * 4;
  int v[4] = {0, 0, 0, 0};
#pragma unroll
  for (int j = 0; j < 4; ++j) { int i = base + j; if (i < NSEG) v[j] = cnt[i]; }
  const int tot = v[0] + v[1] + v[2] + v[3];
  s[t] = tot;
  __syncthreads();
  for (int d = 1; d < 256; d <<= 1) {
    int a = (t >= d) ? s[t - d] : 0;
    __syncthreads();
    s[t] += a;
    __syncthreads();
  }
  if (t == 255) blksum[blockIdx.x] = s[255];
  int run = s[t] - tot;  // exclusive prefix within block
#pragma unroll
  for (int j = 0; j < 4; ++j) {
    int i = base + j;
    if (i < NSEG) { offs[i] = run; run += v[j]; }
  }
}

__global__ __launch_bounds__(512) void scan2_kernel(int* __restrict__ blksum, int n) {
  __shared__ int s[512];
  const int t = threadIdx.x;
  int v = (t < n) ? blksum[t] : 0;
  s[t] = v;
  __syncthreads();
  for (int d = 1; d < 512; d <<= 1) {
    int a = (t >= d) ? s[t - d] : 0;
    __syncthreads();
    s[t] += a;
    __syncthreads();
  }
  if (t < n) blksum[t] = s[t] - v;  // exclusive
}

__global__ __launch_bounds__(256) void scan3_kernel(int* __restrict__ offs,
                                                    const int* __restrict__ blksum,
                                                    int* __restrict__ cursor) {
  int i = blockIdx.x * 256 + threadIdx.x;
  if (i < NSEG) {
    int o = offs[i] + blksum[i >> 10];
    offs[i] = o;
    cursor[i] = o;
  }
  if (i == 0) offs[NSEG] = NR * NE;
}

// ---------------- fill dst-sorted edge list ----------------
__global__ __launch_bounds__(256) void fill_kernel(const int* __restrict__ src,
                                                   const int* __restrict__ dst,
                                                   int* __restrict__ cursor,
                                                   int* __restrict__ esrc) {
  int i = blockIdx.x * 256 + threadIdx.x;
  if (i >= NR * NE) return;
  int r = i / NE;
  int seg = r * NN + dst[i];
  int pos = atomicAdd(&cursor[seg], 1);
  esrc[pos] = src[i];
}

// ---------------- gather aggregate (bf16 x, f32 accum, bf16 out) ----------------
__global__ __launch_bounds__(256) void aggregate_kernel(const u32* __restrict__ xb,
                                                        const int* __restrict__ esrc,
                                                        const int* __restrict__ offs,
                                                        const float* __restrict__ rs_out,
                                                        u32* __restrict__ aggb) {
  const int lane = threadIdx.x & 63;
  const int w = threadIdx.x >> 6;
  const int seg = blockIdx.x * 4 + w;
  if (seg >= NSEG) return;
  const int r = seg / NN;
  const int beg = offs[seg], end = offs[seg + 1];
  const float* rs = rs_out + r * NN;
  float a0 = 0.f, a1 = 0.f;
  int e = beg;
  for (; e + 3 < end; e += 4) {
    int s0 = esrc[e], s1 = esrc[e + 1], s2 = esrc[e + 2], s3 = esrc[e + 3];
    float c0 = rs[s0], c1 = rs[s1], c2 = rs[s2], c3 = rs[s3];
    u32 u0 = xb[(size_t)s0 * 64 + lane];
    u32 u1 = xb[(size_t)s1 * 64 + lane];
    u32 u2 = xb[(size_t)s2 * 64 + lane];
    u32 u3 = xb[(size_t)s3 * 64 + lane];
    a0 = fmaf(lo16(u0), c0, a0); a1 = fmaf(hi16(u0), c0, a1);
    a0 = fmaf(lo16(u1), c1, a0); a1 = fmaf(hi16(u1), c1, a1);
    a0 = fmaf(lo16(u2), c2, a0); a1 = fmaf(hi16(u2), c2, a1);
    a0 = fmaf(lo16(u3), c3, a0); a1 = fmaf(hi16(u3), c3, a1);
  }
  for (; e < end; ++e) {
    int s0 = esrc[e];
    float c0 = rs[s0];
    u32 u0 = xb[(size_t)s0 * 64 + lane];
    a0 = fmaf(lo16(u0), c0, a0);
    a1 = fmaf(hi16(u0), c0, a1);
  }
  aggb[(size_t)seg * 64 + lane] = packbf(a0, a1);
}

// ---------------- prep 1: WWa1[r] = W[r] @ Wa1 (f32) ----------------
__global__ __launch_bounds__(256) void prep_wwa1_kernel(const float* __restrict__ W,
                                                        const float* __restrict__ Wa1,
                                                        float* __restrict__ WWa1) {
  int idx = blockIdx.x * 256 + threadIdx.x;       // r*16384 + i*128 + c
  if (idx >= NR * DD * DD) return;
  int r = idx >> 14, rem = idx & 16383, i = rem >> 7, c = rem & 127;
  const float* wrow = W + (r << 14) + (i << 7);
  float s = 0.f;
#pragma unroll 8
  for (int k = 0; k < DD; ++k) s = fmaf(wrow[k], Wa1[k * DD + c], s);
  WWa1[idx] = s;
}

// ---------------- prep 2: transpose + bf16 hi/lo split, fragment-ready -----------------
__global__ __launch_bounds__(256) void prep_pack_kernel(const float* __restrict__ W,
                                                        const float* __restrict__ WWa1,
                                                        u32* __restrict__ wt_hi,
                                                        u32* __restrict__ wt_lo,
                                                        u32* __restrict__ wwt_hi) {
  int idx = blockIdx.x * 256 + threadIdx.x;       // r*8192 + n*64 + ku
  if (idx >= NR * DD * 64) return;
  int r = idx >> 13, rem = idx & 8191, n = rem >> 6, ku = rem & 63;
  int k0 = ku * 2;
  {
    const float* M = W + (r << 14);
    float w0 = M[k0 * DD + n], w1 = M[(k0 + 1) * DD + n];
    u32 h0 = bfr(w0), h1 = bfr(w1);
    float l0 = w0 - bf2f(h0), l1 = w1 - bf2f(h1);
    wt_hi[idx] = h0 | (h1 << 16);
    wt_lo[idx] = packbf(l0, l1);
  }
  {
    const float* M = WWa1 + (r << 14);
    float w0 = M[k0 * DD + n], w1 = M[(k0 + 1) * DD + n];
    wwt_hi[idx] = bfr(w0) | (bfr(w1) << 16);
  }
}

// ---------------- prep 3: bsum[r][c] = (b_r @ Wa1)[c] + ba1[c] ----------------
__global__ __launch_bounds__(256) void prep_bsum_kernel(const float* __restrict__ b,
                                                        const float* __restrict__ Wa1,
                                                        const float* __restrict__ ba1,
                                                        float* __restrict__ bsum) {
  int idx = blockIdx.x * 256 + threadIdx.x;       // r*128 + c
  if (idx >= NR * DD) return;
  int r = idx >> 7, c = idx & 127;
  float s = ba1[c];
#pragma unroll 8
  for (int k = 0; k < DD; ++k) s = fmaf(b[r * DD + k], Wa1[k * DD + c], s);
  bsum[idx] = s;
}

// ---------------- GEMM per relation: rel (bf16, in-place over aggb) + score ------------
#define MFMA(a, b, c) __builtin_amdgcn_mfma_f32_16x16x32_bf16((a), (b), (c), 0, 0, 0)

__global__ __launch_bounds__(256, 4) void gemm_rs_kernel(
    u32* __restrict__ aggb,            // in: agg (bf16); out: rel (bf16), in-place
    const u32* __restrict__ wt_hi, const u32* __restrict__ wt_lo,
    const u32* __restrict__ wwt_hi,
    const float* __restrict__ rs_in, const float* __restrict__ bias,
    const float* __restrict__ bsum, const float* __restrict__ wa2,
    float* __restrict__ score) {
  __shared__ float scoreS[2][64];
  const int tid = threadIdx.x;
  const int l = tid & 63;
  const int w = tid >> 6;
  const int wr = w >> 1, wc = w & 1;
  const int r = blockIdx.y;
  const int row0 = blockIdx.x * 64;
  const int l15 = l & 15, lg = l >> 4;

  const int arow0 = min(row0 + wr * 32 + l15, NN - 1);
  const int arow1 = min(row0 + wr * 32 + 16 + l15, NN - 1);

  f4_t c1[2][4], c2[2][4];
#pragma unroll
  for (int m = 0; m < 2; ++m)
#pragma unroll
    for (int nf = 0; nf < 4; ++nf) { c1[m][nf] = (f4_t)0.f; c2[m][nf] = (f4_t)0.f; }

  u32* aggr = aggb + (size_t)r * NN * 64;
#pragma unroll
  for (int ks = 0; ks < 4; ++ks) {
    bf8_t a0 = ldfrag(aggr + (size_t)arow0 * 64 + ks * 16 + lg * 4);
    bf8_t a1 = ldfrag(aggr + (size_t)arow1 * 64 + ks * 16 + lg * 4);
#pragma unroll
    for (int nf = 0; nf < 4; ++nf) {
      const int n = wc * 64 + nf * 16 + l15;
      const size_t bo = ((size_t)r * DD + n) * 64 + ks * 16 + lg * 4;
      bf8_t bh = ldfrag(wt_hi + bo);
      bf8_t bl = ldfrag(wt_lo + bo);
      bf8_t gh = ldfrag(wwt_hi + bo);
      c1[0][nf] = MFMA(a0, bh, c1[0][nf]);
      c1[1][nf] = MFMA(a1, bh, c1[1][nf]);
      c1[0][nf] = MFMA(a0, bl, c1[0][nf]);
      c1[1][nf] = MFMA(a1, bl, c1[1][nf]);
      c2[0][nf] = MFMA(a0, gh, c2[0][nf]);
      c2[1][nf] = MFMA(a1, gh, c2[1][nf]);
    }
  }

  // all A-reads of this block's row band are done; safe to overwrite with rel
  __syncthreads();

  float wa2v[4];
#pragma unroll
  for (int nf = 0; nf < 4; ++nf) wa2v[nf] = wa2[wc * 64 + nf * 16 + l15];

#pragma unroll
  for (int m = 0; m < 2; ++m) {
    const int crow0 = row0 + wr * 32 + m * 16 + lg * 4;
    float rsv[4];
#pragma unroll
    for (int reg = 0; reg < 4; ++reg)
      rsv[reg] = rs_in[r * NN + min(crow0 + reg, NN - 1)];
    float part[4] = {0.f, 0.f, 0.f, 0.f};
#pragma unroll
    for (int nf = 0; nf < 4; ++nf) {
      const int col = wc * 64 + nf * 16 + l15;
      const float bv = bias[r * DD + col];
      const float bs = bsum[r * DD + col];
      float relv[4];
#pragma unroll
      for (int reg = 0; reg < 4; ++reg) {
        relv[reg] = fmaf(c1[m][nf][reg], rsv[reg], bv);
        float t = fmaf(c2[m][nf][reg], rsv[reg], bs);
        t = fminf(fmaxf(t, -15.f), 15.f);
        float ex = __expf(2.f * t);
        float th = (ex - 1.f) / (ex + 1.f);
        part[reg] = fmaf(th, wa2v[nf], part[reg]);
      }
      // pack rel pairs (cols 2j,2j+1 live in adjacent lanes) and store bf16
#pragma unroll
      for (int reg = 0; reg < 4; ++reg) {
        float other = __shfl_xor(relv[reg], 1);
        int rowa = crow0 + reg;
        if (((l15 & 1) == 0) && rowa < NN) {
          aggr[(size_t)rowa * 64 + wc * 32 + nf * 8 + (l15 >> 1)] =
              packbf(relv[reg], other);
        }
      }
    }
#pragma unroll
    for (int reg = 0; reg < 4; ++reg) {
      float p = part[reg];
      p += __shfl_xor(p, 1);
      p += __shfl_xor(p, 2);
      p += __shfl_xor(p, 4);
      p += __shfl_xor(p, 8);
      if (l15 == 0) scoreS[wc][wr * 32 + m * 16 + lg * 4 + reg] = p;
    }
  }
  __syncthreads();
  if (tid < 64) {
    int rowa = row0 + tid;
    if (rowa < NN) score[r * NN + rowa] = scoreS[0][tid] + scoreS[1][tid];
  }
}

// ---------------- combine: softmax over relations + weighted sum (streaming) ----------
__global__ __launch_bounds__(256) void combine_kernel(const u32* __restrict__ relb,
                                                      const float* __restrict__ score,
                                                      float* __restrict__ out) {
  int t = blockIdx.x * 256 + threadIdx.x;
  int row = t >> 5;
  int c32 = t & 31;
  if (row >= NN) return;
  float s0 = score[row], s1 = score[NN + row], s2 = score[2 * NN + row];
  float m = fmaxf(s0, fmaxf(s1, s2));
  float e0 = __expf(s0 - m), e1 = __expf(s1 - m), e2 = __expf(s2 - m);
  float inv = 1.f / (e0 + e1 + e2);
  e0 *= inv; e1 *= inv; e2 *= inv;
  size_t o = (size_t)row * 64 + c32 * 2;
  uint2 u0 = *(const uint2*)&relb[o];
  uint2 u1 = *(const uint2*)&relb[(size_t)NN * 64 + o];
  uint2 u2 = *(const uint2*)&relb[2 * (size_t)NN * 64 + o];
  float4 ov;
  ov.x = lo16(u0.x) * e0 + lo16(u1.x) * e1 + lo16(u2.x) * e2;
  ov.y = hi16(u0.x) * e0 + hi16(u1.x) * e1 + hi16(u2.x) * e2;
  ov.z = lo16(u0.y) * e0 + lo16(u1.y) * e1 + lo16(u2.y) * e2;
  ov.w = hi16(u0.y) * e0 + hi16(u1.y) * e1 + hi16(u2.y) * e2;
  *(float4*)&out[(size_t)row * DD + c32 * 4] = ov;
}

extern "C" void kernel_launch(void* const* d_in, const int* in_sizes, int n_in,
                              void* d_out, int out_size, void* d_ws, size_t ws_size,
                              hipStream_t stream) {
  const float* x   = (const float*)d_in[0];
  const int*   src = (const int*)d_in[1];
  const int*   dst = (const int*)d_in[2];
  const float* W   = (const float*)d_in[3];
  const float* b   = (const float*)d_in[4];
  const float* Wa1 = (const float*)d_in[5];
  const float* ba1 = (const float*)d_in[6];
  const float* wa2 = (const float*)d_in[7];
  float* out = (float*)d_out;

  char* ws = (char*)d_ws;
  size_t off = 0;
  u32* aggb = (u32*)(ws + off); off += (size_t)NSEG * 64 * 4;   // 76.8 MB
  u32* xb   = (u32*)(ws + off); off += (size_t)NN * 64 * 4;     // 25.6 MB
  int* cnt_out = (int*)(ws + off); off += (size_t)NSEG * 4;
  int* cnt_in  = (int*)(ws + off); off += (size_t)NSEG * 4;
  float* rs_out = (float*)(ws + off); off += (size_t)NSEG * 4;
  float* rs_in  = (float*)(ws + off); off += (size_t)NSEG * 4;
  float* score  = (float*)(ws + off); off += (size_t)NSEG * 4;
  int* offs    = (int*)(ws + off); off += (size_t)(NSEG + 4) * 4;
  int* cursor  = (int*)(ws + off); off += (size_t)NSEG * 4;
  int* blksum  = (int*)(ws + off); off += (size_t)512 * 4;
  int* esrc    = (int*)(ws + off); off += (size_t)NR * NE * 4;  // 7.68 MB
  float* WWa1  = (float*)(ws + off); off += (size_t)NR * DD * DD * 4;
  u32* wt_hi   = (u32*)(ws + off); off += (size_t)NR * DD * 64 * 4;
  u32* wt_lo   = (u32*)(ws + off); off += (size_t)NR * DD * 64 * 4;
  u32* wwt_hi  = (u32*)(ws + off); off += (size_t)NR * DD * 64 * 4;
  float* bsum  = (float*)(ws + off); off += (size_t)NR * DD * 4;
  if (ws_size < off) return;  // fail loudly (output stays poisoned)

  hipMemsetAsync(cnt_out, 0, (size_t)NSEG * 4 * 2, stream);  // cnt_out + cnt_in

  // weight prep (independent of graph chain)
  prep_wwa1_kernel<<<(NR * DD * DD + 255) / 256, 256, 0, stream>>>(W, Wa1, WWa1);
  prep_pack_kernel<<<(NR * DD * 64 + 255) / 256, 256, 0, stream>>>(W, WWa1, wt_hi, wt_lo,
                                                                   wwt_hi);
  prep_bsum_kernel<<<(NR * DD + 255) / 256, 256, 0, stream>>>(b, Wa1, ba1, bsum);

  convert_x_kernel<<<(NN * 64 + 255) / 256, 256, 0, stream>>>(x, xb);
  degree_kernel<<<(NR * NE + 255) / 256, 256, 0, stream>>>(src, dst, cnt_out, cnt_in);
  rs_kernel<<<(NSEG + 255) / 256, 256, 0, stream>>>(cnt_out, cnt_in, rs_out, rs_in);
  scan1_kernel<<<NBLK, 256, 0, stream>>>(cnt_in, offs, blksum);
  scan2_kernel<<<1, 512, 0, stream>>>(blksum, NBLK);
  scan3_kernel<<<(NSEG + 255) / 256, 256, 0, stream>>>(offs, blksum, cursor);
  fill_kernel<<<(NR * NE + 255) / 256, 256, 0, stream>>>(src, dst, cursor, esrc);
  aggregate_kernel<<<(NSEG + 3) / 4, 256, 0, stream>>>(xb, esrc, offs, rs_out, aggb);

  dim3 gg((NN + 63) / 64, NR);
  gemm_rs_kernel<<<gg, 256, 0, stream>>>(aggb, wt_hi, wt_lo, wwt_hi, rs_in, b, bsum,
                                         wa2, score);
  combine_kernel<<<(NN * 32 + 255) / 256, 256, 0, stream>>>(aggb, score, out);
}

// Round 6
// 563.729 us; speedup vs baseline: 6.5612x; 1.0962x over previous
//
#include <hip/hip_runtime.h>

#define NN 100000
#define NE 640000
#define NR 3
#define DD 128
#define NSEG (NR * NN)            // 300000 segments (relation, node)
#define SCAN_BLK 1024             // elements per scan block
#define NBLK ((NSEG + SCAN_BLK - 1) / SCAN_BLK)   // 293

typedef unsigned int u32;
typedef short bf8_t __attribute__((ext_vector_type(8)));   // 8 bf16 (4 VGPRs)
typedef float f4_t __attribute__((ext_vector_type(4)));

union U4 { uint4 u; bf8_t b; };

__device__ __forceinline__ u32 bfr(float f) {          // f32 -> bf16 bits (RNE)
  u32 u = __float_as_uint(f);
  return (u + 0x7fffu + ((u >> 16) & 1u)) >> 16;
}
__device__ __forceinline__ u32 packbf(float a, float b) {
  return bfr(a) | (bfr(b) << 16);
}
__device__ __forceinline__ float lo16(u32 u) { return __uint_as_float(u << 16); }
__device__ __forceinline__ float hi16(u32 u) { return __uint_as_float(u & 0xffff0000u); }
__device__ __forceinline__ float bf2f(u32 bits) { return __uint_as_float(bits << 16); }

__device__ __forceinline__ bf8_t ldfrag(const u32* p) {
  U4 t; t.u = *(const uint4*)p; return t.b;
}

// ---------------- x -> packed bf16 ----------------
__global__ __launch_bounds__(256) void convert_x_kernel(const float* __restrict__ x,
                                                        u32* __restrict__ xb) {
  int i = blockIdx.x * 256 + threadIdx.x;
  if (i >= NN * 64) return;
  float2 v = ((const float2*)x)[i];
  xb[i] = packbf(v.x, v.y);
}

// ---------------- degree counting ----------------
__global__ __launch_bounds__(256) void degree_kernel(const int* __restrict__ src,
                                                     const int* __restrict__ dst,
                                                     int* __restrict__ cnt_out,
                                                     int* __restrict__ cnt_in) {
  int i = blockIdx.x * 256 + threadIdx.x;
  if (i >= NR * NE) return;
  int r = i / NE;
  atomicAdd(&cnt_out[r * NN + src[i]], 1);
  atomicAdd(&cnt_in[r * NN + dst[i]], 1);
}

__global__ __launch_bounds__(256) void rs_kernel(const int* __restrict__ cnt_out,
                                                 const int* __restrict__ cnt_in,
                                                 float* __restrict__ rs_out,
                                                 float* __restrict__ rs_in) {
  int i = blockIdx.x * 256 + threadIdx.x;
  if (i >= NSEG) return;
  int co = cnt_out[i]; if (co < 1) co = 1;
  int ci = cnt_in[i]; if (ci < 1) ci = 1;
  rs_out[i] = rsqrtf((float)co);
  rs_in[i]  = rsqrtf((float)ci);
}

// ---------------- counting-sort scan (3 kernels) ----------------
__global__ __launch_bounds__(256) void scan1_kernel(const int* __restrict__ cnt,
                                                    int* __restrict__ offs,
                                                    int* __restrict__ blksum) {
  __shared__ int s[256];
  const int t = threadIdx.x;
  const int base = blockIdx.x * SCAN_BLK + t * 4;
  int v[4] = {0, 0, 0, 0};
#pragma unroll
  for (int j = 0; j < 4; ++j) { int i = base + j; if (i < NSEG) v[j] = cnt[i]; }
  const int tot = v[0] + v[1] + v[2] + v[3];
  s[t] = tot;
  __syncthreads();
  for (int d = 1; d < 256; d <<= 1) {
    int a = (t >= d) ? s[t - d] : 0;
    __syncthreads();
    s[t] += a;
    __syncthreads();
  }
  if (t == 255) blksum[blockIdx.x] = s[255];
  int run = s[t] - tot;  // exclusive prefix within block
#pragma unroll
  for (int j = 0; j < 4; ++j) {
    int i = base + j;
    if (i < NSEG) { offs[i] = run; run += v[j]; }
  }
}

__global__ __launch_bounds__(512) void scan2_kernel(int* __restrict__ blksum, int n) {
  __shared__ int s[512];
  const int t = threadIdx.x;
  int v = (t < n) ? blksum[t] : 0;
  s[t] = v;
  __syncthreads();
  for (int d = 1; d < 512; d <<= 1) {
    int a = (t >= d) ? s[t - d] : 0;
    __syncthreads();
    s[t] += a;
    __syncthreads();
  }
  if (t < n) blksum[t] = s[t] - v;  // exclusive
}

__global__ __launch_bounds__(256) void scan3_kernel(int* __restrict__ offs,
                                                    const int* __restrict__ blksum,
                                                    int* __restrict__ cursor) {
  int i = blockIdx.x * 256 + threadIdx.x;
  if (i < NSEG) {
    int o = offs[i] + blksum[i >> 10];
    offs[i] = o;
    cursor[i] = o;
  }
  if (i == 0) offs[NSEG] = NR * NE;
}

// ---------------- fill dst-sorted edge list ----------------
__global__ __launch_bounds__(256) void fill_kernel(const int* __restrict__ src,
                                                   const int* __restrict__ dst,
                                                   int* __restrict__ cursor,
                                                   int* __restrict__ esrc) {
  int i = blockIdx.x * 256 + threadIdx.x;
  if (i >= NR * NE) return;
  int r = i / NE;
  int seg = r * NN + dst[i];
  int pos = atomicAdd(&cursor[seg], 1);
  esrc[pos] = src[i];
}

// ---------------- gather aggregate (bf16 x, f32 accum, bf16 out) ----------------
// 16 lanes per segment (uint4 = 16B/lane), 4 segments per wave, 16 per block.
__global__ __launch_bounds__(256) void aggregate_kernel(const u32* __restrict__ xb,
                                                        const int* __restrict__ esrc,
                                                        const int* __restrict__ offs,
                                                        const float* __restrict__ rs_out,
                                                        u32* __restrict__ aggb) {
  const int lane16 = threadIdx.x & 15;
  const int grp = threadIdx.x >> 4;           // 0..15 segment slot in block
  const int seg = blockIdx.x * 16 + grp;
  if (seg >= NSEG) return;
  const int r = seg / NN;
  const int beg = offs[seg], end = offs[seg + 1];
  const float* rs = rs_out + r * NN;
  float a[8] = {0.f, 0.f, 0.f, 0.f, 0.f, 0.f, 0.f, 0.f};
  int e = beg;
  for (; e + 1 < end; e += 2) {
    int s0 = esrc[e], s1 = esrc[e + 1];
    float c0 = rs[s0], c1 = rs[s1];
    uint4 u0 = *(const uint4*)&xb[(size_t)s0 * 64 + lane16 * 4];
    uint4 u1 = *(const uint4*)&xb[(size_t)s1 * 64 + lane16 * 4];
    a[0] = fmaf(lo16(u0.x), c0, a[0]); a[1] = fmaf(hi16(u0.x), c0, a[1]);
    a[2] = fmaf(lo16(u0.y), c0, a[2]); a[3] = fmaf(hi16(u0.y), c0, a[3]);
    a[4] = fmaf(lo16(u0.z), c0, a[4]); a[5] = fmaf(hi16(u0.z), c0, a[5]);
    a[6] = fmaf(lo16(u0.w), c0, a[6]); a[7] = fmaf(hi16(u0.w), c0, a[7]);
    a[0] = fmaf(lo16(u1.x), c1, a[0]); a[1] = fmaf(hi16(u1.x), c1, a[1]);
    a[2] = fmaf(lo16(u1.y), c1, a[2]); a[3] = fmaf(hi16(u1.y), c1, a[3]);
    a[4] = fmaf(lo16(u1.z), c1, a[4]); a[5] = fmaf(hi16(u1.z), c1, a[5]);
    a[6] = fmaf(lo16(u1.w), c1, a[6]); a[7] = fmaf(hi16(u1.w), c1, a[7]);
  }
  if (e < end) {
    int s0 = esrc[e];
    float c0 = rs[s0];
    uint4 u0 = *(const uint4*)&xb[(size_t)s0 * 64 + lane16 * 4];
    a[0] = fmaf(lo16(u0.x), c0, a[0]); a[1] = fmaf(hi16(u0.x), c0, a[1]);
    a[2] = fmaf(lo16(u0.y), c0, a[2]); a[3] = fmaf(hi16(u0.y), c0, a[3]);
    a[4] = fmaf(lo16(u0.z), c0, a[4]); a[5] = fmaf(hi16(u0.z), c0, a[5]);
    a[6] = fmaf(lo16(u0.w), c0, a[6]); a[7] = fmaf(hi16(u0.w), c0, a[7]);
  }
  uint4 o;
  o.x = packbf(a[0], a[1]);
  o.y = packbf(a[2], a[3]);
  o.z = packbf(a[4], a[5]);
  o.w = packbf(a[6], a[7]);
  *(uint4*)&aggb[(size_t)seg * 64 + lane16 * 4] = o;
}

// ---------------- prep 1: WWa1[r] = W[r] @ Wa1 (f32) ----------------
__global__ __launch_bounds__(256) void prep_wwa1_kernel(const float* __restrict__ W,
                                                        const float* __restrict__ Wa1,
                                                        float* __restrict__ WWa1) {
  int idx = blockIdx.x * 256 + threadIdx.x;       // r*16384 + i*128 + c
  if (idx >= NR * DD * DD) return;
  int r = idx >> 14, rem = idx & 16383, i = rem >> 7, c = rem & 127;
  const float* wrow = W + (r << 14) + (i << 7);
  float s = 0.f;
#pragma unroll 8
  for (int k = 0; k < DD; ++k) s = fmaf(wrow[k], Wa1[k * DD + c], s);
  WWa1[idx] = s;
}

// ---------------- prep 2: transpose + bf16 hi/lo split, fragment-ready -----------------
__global__ __launch_bounds__(256) void prep_pack_kernel(const float* __restrict__ W,
                                                        const float* __restrict__ WWa1,
                                                        u32* __restrict__ wt_hi,
                                                        u32* __restrict__ wt_lo,
                                                        u32* __restrict__ wwt_hi) {
  int idx = blockIdx.x * 256 + threadIdx.x;       // r*8192 + n*64 + ku
  if (idx >= NR * DD * 64) return;
  int r = idx >> 13, rem = idx & 8191, n = rem >> 6, ku = rem & 63;
  int k0 = ku * 2;
  {
    const float* M = W + (r << 14);
    float w0 = M[k0 * DD + n], w1 = M[(k0 + 1) * DD + n];
    u32 h0 = bfr(w0), h1 = bfr(w1);
    float l0 = w0 - bf2f(h0), l1 = w1 - bf2f(h1);
    wt_hi[idx] = h0 | (h1 << 16);
    wt_lo[idx] = packbf(l0, l1);
  }
  {
    const float* M = WWa1 + (r << 14);
    float w0 = M[k0 * DD + n], w1 = M[(k0 + 1) * DD + n];
    wwt_hi[idx] = bfr(w0) | (bfr(w1) << 16);
  }
}

// ---------------- prep 3: bsum[r][c] = (b_r @ Wa1)[c] + ba1[c] ----------------
__global__ __launch_bounds__(256) void prep_bsum_kernel(const float* __restrict__ b,
                                                        const float* __restrict__ Wa1,
                                                        const float* __restrict__ ba1,
                                                        float* __restrict__ bsum) {
  int idx = blockIdx.x * 256 + threadIdx.x;       // r*128 + c
  if (idx >= NR * DD) return;
  int r = idx >> 7, c = idx & 127;
  float s = ba1[c];
#pragma unroll 8
  for (int k = 0; k < DD; ++k) s = fmaf(b[r * DD + k], Wa1[k * DD + c], s);
  bsum[idx] = s;
}

// ---------------- GEMM per relation: rel (bf16, in-place over aggb) + score ------------
// Wave tile 64 rows x 64 cols (4 row-frags); block 128x128 (2 wr x 2 wc).
#define MFMA(a, b, c) __builtin_amdgcn_mfma_f32_16x16x32_bf16((a), (b), (c), 0, 0, 0)

__global__ __launch_bounds__(256, 2) void gemm_rs_kernel(
    u32* __restrict__ aggb,            // in: agg (bf16); out: rel (bf16), in-place
    const u32* __restrict__ wt_hi, const u32* __restrict__ wt_lo,
    const u32* __restrict__ wwt_hi,
    const float* __restrict__ rs_in, const float* __restrict__ bias,
    const float* __restrict__ bsum, const float* __restrict__ wa2,
    float* __restrict__ score) {
  __shared__ float scoreS[2][128];
  const int tid = threadIdx.x;
  const int l = tid & 63;
  const int w = tid >> 6;
  const int wr = w >> 1, wc = w & 1;
  const int r = blockIdx.y;
  const int row0 = blockIdx.x * 128;
  const int l15 = l & 15, lg = l >> 4;

  int arow[4];
#pragma unroll
  for (int rf = 0; rf < 4; ++rf)
    arow[rf] = min(row0 + wr * 64 + rf * 16 + l15, NN - 1);

  f4_t c1[4][4], c2[4][4];
#pragma unroll
  for (int rf = 0; rf < 4; ++rf)
#pragma unroll
    for (int nf = 0; nf < 4; ++nf) { c1[rf][nf] = (f4_t)0.f; c2[rf][nf] = (f4_t)0.f; }

  u32* aggr = aggb + (size_t)r * NN * 64;
#pragma unroll
  for (int ks = 0; ks < 4; ++ks) {
    bf8_t a[4];
#pragma unroll
    for (int rf = 0; rf < 4; ++rf)
      a[rf] = ldfrag(aggr + (size_t)arow[rf] * 64 + ks * 16 + lg * 4);
#pragma unroll
    for (int nf = 0; nf < 4; ++nf) {
      const int n = wc * 64 + nf * 16 + l15;
      const size_t bo = ((size_t)r * DD + n) * 64 + ks * 16 + lg * 4;
      bf8_t bh = ldfrag(wt_hi + bo);
      bf8_t bl = ldfrag(wt_lo + bo);
      bf8_t gh = ldfrag(wwt_hi + bo);
#pragma unroll
      for (int rf = 0; rf < 4; ++rf) c1[rf][nf] = MFMA(a[rf], bh, c1[rf][nf]);
#pragma unroll
      for (int rf = 0; rf < 4; ++rf) c1[rf][nf] = MFMA(a[rf], bl, c1[rf][nf]);
#pragma unroll
      for (int rf = 0; rf < 4; ++rf) c2[rf][nf] = MFMA(a[rf], gh, c2[rf][nf]);
    }
  }

  // all A-reads of this wave's row band are done; safe to overwrite with rel
  __syncthreads();

  float wa2v[4];
#pragma unroll
  for (int nf = 0; nf < 4; ++nf) wa2v[nf] = wa2[wc * 64 + nf * 16 + l15];

#pragma unroll
  for (int rf = 0; rf < 4; ++rf) {
    const int crow0 = row0 + wr * 64 + rf * 16 + lg * 4;
    float rsv[4];
#pragma unroll
    for (int reg = 0; reg < 4; ++reg)
      rsv[reg] = rs_in[r * NN + min(crow0 + reg, NN - 1)];
    float part[4] = {0.f, 0.f, 0.f, 0.f};
#pragma unroll
    for (int nf = 0; nf < 4; ++nf) {
      const int col = wc * 64 + nf * 16 + l15;
      const float bv = bias[r * DD + col];
      const float bs = bsum[r * DD + col];
      float relv[4];
#pragma unroll
      for (int reg = 0; reg < 4; ++reg) {
        relv[reg] = fmaf(c1[rf][nf][reg], rsv[reg], bv);
        float t = fmaf(c2[rf][nf][reg], rsv[reg], bs);
        t = fminf(fmaxf(t, -15.f), 15.f);
        float ex = __expf(2.f * t);
        float th = (ex - 1.f) / (ex + 1.f);
        part[reg] = fmaf(th, wa2v[nf], part[reg]);
      }
      // pack rel pairs (cols 2j,2j+1 live in adjacent lanes) and store bf16
#pragma unroll
      for (int reg = 0; reg < 4; ++reg) {
        float other = __shfl_xor(relv[reg], 1);
        int rowa = crow0 + reg;
        if (((l15 & 1) == 0) && rowa < NN) {
          aggr[(size_t)rowa * 64 + wc * 32 + nf * 8 + (l15 >> 1)] =
              packbf(relv[reg], other);
        }
      }
    }
#pragma unroll
    for (int reg = 0; reg < 4; ++reg) {
      float p = part[reg];
      p += __shfl_xor(p, 1);
      p += __shfl_xor(p, 2);
      p += __shfl_xor(p, 4);
      p += __shfl_xor(p, 8);
      if (l15 == 0) scoreS[wc][wr * 64 + rf * 16 + lg * 4 + reg] = p;
    }
  }
  __syncthreads();
  if (tid < 128) {
    int rowa = row0 + tid;
    if (rowa < NN) score[r * NN + rowa] = scoreS[0][tid] + scoreS[1][tid];
  }
}

// ---------------- combine: softmax over relations + weighted sum (streaming) ----------
__global__ __launch_bounds__(256) void combine_kernel(const u32* __restrict__ relb,
                                                      const float* __restrict__ score,
                                                      float* __restrict__ out) {
  int t = blockIdx.x * 256 + threadIdx.x;
  int row = t >> 5;
  int c32 = t & 31;
  if (row >= NN) return;
  float s0 = score[row], s1 = score[NN + row], s2 = score[2 * NN + row];
  float m = fmaxf(s0, fmaxf(s1, s2));
  float e0 = __expf(s0 - m), e1 = __expf(s1 - m), e2 = __expf(s2 - m);
  float inv = 1.f / (e0 + e1 + e2);
  e0 *= inv; e1 *= inv; e2 *= inv;
  size_t o = (size_t)row * 64 + c32 * 2;
  uint2 u0 = *(const uint2*)&relb[o];
  uint2 u1 = *(const uint2*)&relb[(size_t)NN * 64 + o];
  uint2 u2 = *(const uint2*)&relb[2 * (size_t)NN * 64 + o];
  float4 ov;
  ov.x = lo16(u0.x) * e0 + lo16(u1.x) * e1 + lo16(u2.x) * e2;
  ov.y = hi16(u0.x) * e0 + hi16(u1.x) * e1 + hi16(u2.x) * e2;
  ov.z = lo16(u0.y) * e0 + lo16(u1.y) * e1 + lo16(u2.y) * e2;
  ov.w = hi16(u0.y) * e0 + hi16(u1.y) * e1 + hi16(u2.y) * e2;
  *(float4*)&out[(size_t)row * DD + c32 * 4] = ov;
}

extern "C" void kernel_launch(void* const* d_in, const int* in_sizes, int n_in,
                              void* d_out, int out_size, void* d_ws, size_t ws_size,
                              hipStream_t stream) {
  const float* x   = (const float*)d_in[0];
  const int*   src = (const int*)d_in[1];
  const int*   dst = (const int*)d_in[2];
  const float* W   = (const float*)d_in[3];
  const float* b   = (const float*)d_in[4];
  const float* Wa1 = (const float*)d_in[5];
  const float* ba1 = (const float*)d_in[6];
  const float* wa2 = (const float*)d_in[7];
  float* out = (float*)d_out;

  char* ws = (char*)d_ws;
  size_t off = 0;
  u32* aggb = (u32*)(ws + off); off += (size_t)NSEG * 64 * 4;   // 76.8 MB
  u32* xb   = (u32*)(ws + off); off += (size_t)NN * 64 * 4;     // 25.6 MB
  int* cnt_out = (int*)(ws + off); off += (size_t)NSEG * 4;
  int* cnt_in  = (int*)(ws + off); off += (size_t)NSEG * 4;
  float* rs_out = (float*)(ws + off); off += (size_t)NSEG * 4;
  float* rs_in  = (float*)(ws + off); off += (size_t)NSEG * 4;
  float* score  = (float*)(ws + off); off += (size_t)NSEG * 4;
  int* offs    = (int*)(ws + off); off += (size_t)(NSEG + 4) * 4;
  int* cursor  = (int*)(ws + off); off += (size_t)NSEG * 4;
  int* blksum  = (int*)(ws + off); off += (size_t)512 * 4;
  int* esrc    = (int*)(ws + off); off += (size_t)NR * NE * 4;  // 7.68 MB
  float* WWa1  = (float*)(ws + off); off += (size_t)NR * DD * DD * 4;
  u32* wt_hi   = (u32*)(ws + off); off += (size_t)NR * DD * 64 * 4;
  u32* wt_lo   = (u32*)(ws + off); off += (size_t)NR * DD * 64 * 4;
  u32* wwt_hi  = (u32*)(ws + off); off += (size_t)NR * DD * 64 * 4;
  float* bsum  = (float*)(ws + off); off += (size_t)NR * DD * 4;
  if (ws_size < off) return;  // fail loudly (output stays poisoned)

  hipMemsetAsync(cnt_out, 0, (size_t)NSEG * 4 * 2, stream);  // cnt_out + cnt_in

  // weight prep (independent of graph chain)
  prep_wwa1_kernel<<<(NR * DD * DD + 255) / 256, 256, 0, stream>>>(W, Wa1, WWa1);
  prep_pack_kernel<<<(NR * DD * 64 + 255) / 256, 256, 0, stream>>>(W, WWa1, wt_hi, wt_lo,
                                                                   wwt_hi);
  prep_bsum_kernel<<<(NR * DD + 255) / 256, 256, 0, stream>>>(b, Wa1, ba1, bsum);

  convert_x_kernel<<<(NN * 64 + 255) / 256, 256, 0, stream>>>(x, xb);
  degree_kernel<<<(NR * NE + 255) / 256, 256, 0, stream>>>(src, dst, cnt_out, cnt_in);
  rs_kernel<<<(NSEG + 255) / 256, 256, 0, stream>>>(cnt_out, cnt_in, rs_out, rs_in);
  scan1_kernel<<<NBLK, 256, 0, stream>>>(cnt_in, offs, blksum);
  scan2_kernel<<<1, 512, 0, stream>>>(blksum, NBLK);
  scan3_kernel<<<(NSEG + 255) / 256, 256, 0, stream>>>(offs, blksum, cursor);
  fill_kernel<<<(NR * NE + 255) / 256, 256, 0, stream>>>(src, dst, cursor, esrc);
  aggregate_kernel<<<(NSEG + 15) / 16, 256, 0, stream>>>(xb, esrc, offs, rs_out, aggb);

  dim3 gg((NN + 127) / 128, NR);
  gemm_rs_kernel<<<gg, 256, 0, stream>>>(aggb, wt_hi, wt_lo, wwt_hi, rs_in, b, bsum,
                                         wa2, score);
  combine_kernel<<<(NN * 32 + 255) / 256, 256, 0, stream>>>(aggb, score, out);
}

// Round 7
// 539.220 us; speedup vs baseline: 6.8594x; 1.0455x over previous
//
#include <hip/hip_runtime.h>

#define NN 100000
#define NE 640000
#define NR 3
#define DD 128
#define NSEG (NR * NN)            // 300000 segments (relation, node)
#define SCAN_BLK 1024             // elements per scan block
#define NBLK ((NSEG + SCAN_BLK - 1) / SCAN_BLK)   // 293

typedef unsigned int u32;
typedef short bf8_t __attribute__((ext_vector_type(8)));   // 8 bf16 (4 VGPRs)
typedef float f4_t __attribute__((ext_vector_type(4)));

union U4 { uint4 u; bf8_t b; };

__device__ __forceinline__ u32 bfr(float f) {          // f32 -> bf16 bits (RNE)
  u32 u = __float_as_uint(f);
  return (u + 0x7fffu + ((u >> 16) & 1u)) >> 16;
}
__device__ __forceinline__ u32 packbf(float a, float b) {
  return bfr(a) | (bfr(b) << 16);
}
__device__ __forceinline__ float lo16(u32 u) { return __uint_as_float(u << 16); }
__device__ __forceinline__ float hi16(u32 u) { return __uint_as_float(u & 0xffff0000u); }
__device__ __forceinline__ float bf2f(u32 bits) { return __uint_as_float(bits << 16); }

__device__ __forceinline__ bf8_t ldfrag(const u32* p) {
  U4 t; t.u = *(const uint4*)p; return t.b;
}

// async global->LDS, 16B per lane; dest = wave-uniform base + lane*16
__device__ __forceinline__ void gload_lds16(const u32* g, u32* l) {
  __builtin_amdgcn_global_load_lds((const __attribute__((address_space(1))) void*)g,
                                   (__attribute__((address_space(3))) void*)l, 16, 0, 0);
}

// ---------------- x -> packed bf16 ----------------
__global__ __launch_bounds__(256) void convert_x_kernel(const float* __restrict__ x,
                                                        u32* __restrict__ xb) {
  int i = blockIdx.x * 256 + threadIdx.x;
  if (i >= NN * 64) return;
  float2 v = ((const float2*)x)[i];
  xb[i] = packbf(v.x, v.y);
}

// ---------------- degree counting ----------------
__global__ __launch_bounds__(256) void degree_kernel(const int* __restrict__ src,
                                                     const int* __restrict__ dst,
                                                     int* __restrict__ cnt_out,
                                                     int* __restrict__ cnt_in) {
  int i = blockIdx.x * 256 + threadIdx.x;
  if (i >= NR * NE) return;
  int r = i / NE;
  atomicAdd(&cnt_out[r * NN + src[i]], 1);
  atomicAdd(&cnt_in[r * NN + dst[i]], 1);
}

__global__ __launch_bounds__(256) void rs_kernel(const int* __restrict__ cnt_out,
                                                 const int* __restrict__ cnt_in,
                                                 float* __restrict__ rs_out,
                                                 float* __restrict__ rs_in) {
  int i = blockIdx.x * 256 + threadIdx.x;
  if (i >= NSEG) return;
  int co = cnt_out[i]; if (co < 1) co = 1;
  int ci = cnt_in[i]; if (ci < 1) ci = 1;
  rs_out[i] = rsqrtf((float)co);
  rs_in[i]  = rsqrtf((float)ci);
}

// ---------------- counting-sort scan (3 kernels) ----------------
__global__ __launch_bounds__(256) void scan1_kernel(const int* __restrict__ cnt,
                                                    int* __restrict__ offs,
                                                    int* __restrict__ blksum) {
  __shared__ int s[256];
  const int t = threadIdx.x;
  const int base = blockIdx.x * SCAN_BLK + t * 4;
  int v[4] = {0, 0, 0, 0};
#pragma unroll
  for (int j = 0; j < 4; ++j) { int i = base + j; if (i < NSEG) v[j] = cnt[i]; }
  const int tot = v[0] + v[1] + v[2] + v[3];
  s[t] = tot;
  __syncthreads();
  for (int d = 1; d < 256; d <<= 1) {
    int a = (t >= d) ? s[t - d] : 0;
    __syncthreads();
    s[t] += a;
    __syncthreads();
  }
  if (t == 255) blksum[blockIdx.x] = s[255];
  int run = s[t] - tot;  // exclusive prefix within block
#pragma unroll
  for (int j = 0; j < 4; ++j) {
    int i = base + j;
    if (i < NSEG) { offs[i] = run; run += v[j]; }
  }
}

__global__ __launch_bounds__(512) void scan2_kernel(int* __restrict__ blksum, int n) {
  __shared__ int s[512];
  const int t = threadIdx.x;
  int v = (t < n) ? blksum[t] : 0;
  s[t] = v;
  __syncthreads();
  for (int d = 1; d < 512; d <<= 1) {
    int a = (t >= d) ? s[t - d] : 0;
    __syncthreads();
    s[t] += a;
    __syncthreads();
  }
  if (t < n) blksum[t] = s[t] - v;  // exclusive
}

__global__ __launch_bounds__(256) void scan3_kernel(int* __restrict__ offs,
                                                    const int* __restrict__ blksum,
                                                    int* __restrict__ cursor) {
  int i = blockIdx.x * 256 + threadIdx.x;
  if (i < NSEG) {
    int o = offs[i] + blksum[i >> 10];
    offs[i] = o;
    cursor[i] = o;
  }
  if (i == 0) offs[NSEG] = NR * NE;
}

// ---------------- fill dst-sorted edge list ----------------
__global__ __launch_bounds__(256) void fill_kernel(const int* __restrict__ src,
                                                   const int* __restrict__ dst,
                                                   int* __restrict__ cursor,
                                                   int* __restrict__ esrc) {
  int i = blockIdx.x * 256 + threadIdx.x;
  if (i >= NR * NE) return;
  int r = i / NE;
  int seg = r * NN + dst[i];
  int pos = atomicAdd(&cursor[seg], 1);
  esrc[pos] = src[i];
}

// ---------------- gather aggregate (bf16 x, f32 accum, bf16 out) ----------------
// 16 lanes per segment (uint4 = 16B/lane), 16 segments per block.
__global__ __launch_bounds__(256) void aggregate_kernel(const u32* __restrict__ xb,
                                                        const int* __restrict__ esrc,
                                                        const int* __restrict__ offs,
                                                        const float* __restrict__ rs_out,
                                                        u32* __restrict__ aggb) {
  const int lane16 = threadIdx.x & 15;
  const int grp = threadIdx.x >> 4;           // 0..15 segment slot in block
  const int seg = blockIdx.x * 16 + grp;
  if (seg >= NSEG) return;
  const int r = seg / NN;
  const int beg = offs[seg], end = offs[seg + 1];
  const float* rs = rs_out + r * NN;
  float a[8] = {0.f, 0.f, 0.f, 0.f, 0.f, 0.f, 0.f, 0.f};
  int e = beg;
  for (; e + 1 < end; e += 2) {
    int s0 = esrc[e], s1 = esrc[e + 1];
    float c0 = rs[s0], c1 = rs[s1];
    uint4 u0 = *(const uint4*)&xb[(size_t)s0 * 64 + lane16 * 4];
    uint4 u1 = *(const uint4*)&xb[(size_t)s1 * 64 + lane16 * 4];
    a[0] = fmaf(lo16(u0.x), c0, a[0]); a[1] = fmaf(hi16(u0.x), c0, a[1]);
    a[2] = fmaf(lo16(u0.y), c0, a[2]); a[3] = fmaf(hi16(u0.y), c0, a[3]);
    a[4] = fmaf(lo16(u0.z), c0, a[4]); a[5] = fmaf(hi16(u0.z), c0, a[5]);
    a[6] = fmaf(lo16(u0.w), c0, a[6]); a[7] = fmaf(hi16(u0.w), c0, a[7]);
    a[0] = fmaf(lo16(u1.x), c1, a[0]); a[1] = fmaf(hi16(u1.x), c1, a[1]);
    a[2] = fmaf(lo16(u1.y), c1, a[2]); a[3] = fmaf(hi16(u1.y), c1, a[3]);
    a[4] = fmaf(lo16(u1.z), c1, a[4]); a[5] = fmaf(hi16(u1.z), c1, a[5]);
    a[6] = fmaf(lo16(u1.w), c1, a[6]); a[7] = fmaf(hi16(u1.w), c1, a[7]);
  }
  if (e < end) {
    int s0 = esrc[e];
    float c0 = rs[s0];
    uint4 u0 = *(const uint4*)&xb[(size_t)s0 * 64 + lane16 * 4];
    a[0] = fmaf(lo16(u0.x), c0, a[0]); a[1] = fmaf(hi16(u0.x), c0, a[1]);
    a[2] = fmaf(lo16(u0.y), c0, a[2]); a[3] = fmaf(hi16(u0.y), c0, a[3]);
    a[4] = fmaf(lo16(u0.z), c0, a[4]); a[5] = fmaf(hi16(u0.z), c0, a[5]);
    a[6] = fmaf(lo16(u0.w), c0, a[6]); a[7] = fmaf(hi16(u0.w), c0, a[7]);
  }
  uint4 o;
  o.x = packbf(a[0], a[1]);
  o.y = packbf(a[2], a[3]);
  o.z = packbf(a[4], a[5]);
  o.w = packbf(a[6], a[7]);
  *(uint4*)&aggb[(size_t)seg * 64 + lane16 * 4] = o;
}

// ---------------- prep 1: WWa1[r] = W[r] @ Wa1 (f32) ----------------
__global__ __launch_bounds__(256) void prep_wwa1_kernel(const float* __restrict__ W,
                                                        const float* __restrict__ Wa1,
                                                        float* __restrict__ WWa1) {
  int idx = blockIdx.x * 256 + threadIdx.x;       // r*16384 + i*128 + c
  if (idx >= NR * DD * DD) return;
  int r = idx >> 14, rem = idx & 16383, i = rem >> 7, c = rem & 127;
  const float* wrow = W + (r << 14) + (i << 7);
  float s = 0.f;
#pragma unroll 8
  for (int k = 0; k < DD; ++k) s = fmaf(wrow[k], Wa1[k * DD + c], s);
  WWa1[idx] = s;
}

// ---------------- prep 2: transpose + bf16 hi/lo split, fragment-ready -----------------
// layout [r][n][ku]: bf16-pair rows along k (64 u32 per n-row)
__global__ __launch_bounds__(256) void prep_pack_kernel(const float* __restrict__ W,
                                                        const float* __restrict__ WWa1,
                                                        u32* __restrict__ wt_hi,
                                                        u32* __restrict__ wt_lo,
                                                        u32* __restrict__ wwt_hi) {
  int idx = blockIdx.x * 256 + threadIdx.x;       // r*8192 + n*64 + ku
  if (idx >= NR * DD * 64) return;
  int r = idx >> 13, rem = idx & 8191, n = rem >> 6, ku = rem & 63;
  int k0 = ku * 2;
  {
    const float* M = W + (r << 14);
    float w0 = M[k0 * DD + n], w1 = M[(k0 + 1) * DD + n];
    u32 h0 = bfr(w0), h1 = bfr(w1);
    float l0 = w0 - bf2f(h0), l1 = w1 - bf2f(h1);
    wt_hi[idx] = h0 | (h1 << 16);
    wt_lo[idx] = packbf(l0, l1);
  }
  {
    const float* M = WWa1 + (r << 14);
    float w0 = M[k0 * DD + n], w1 = M[(k0 + 1) * DD + n];
    wwt_hi[idx] = bfr(w0) | (bfr(w1) << 16);
  }
}

// ---------------- prep 3: bsum[r][c] = (b_r @ Wa1)[c] + ba1[c] ----------------
__global__ __launch_bounds__(256) void prep_bsum_kernel(const float* __restrict__ b,
                                                        const float* __restrict__ Wa1,
                                                        const float* __restrict__ ba1,
                                                        float* __restrict__ bsum) {
  int idx = blockIdx.x * 256 + threadIdx.x;       // r*128 + c
  if (idx >= NR * DD) return;
  int r = idx >> 7, c = idx & 127;
  float s = ba1[c];
#pragma unroll 8
  for (int k = 0; k < DD; ++k) s = fmaf(b[r * DD + k], Wa1[k * DD + c], s);
  bsum[idx] = s;
}

#define MFMA(a, b, c) __builtin_amdgcn_mfma_f32_16x16x32_bf16((a), (b), (c), 0, 0, 0)

// ============ pass 1: scores + softmax -> e[3][N], w[3][N]=e*rs_in ============
// Block: 128 rows x 128 cols, 4 waves (2 wr x 2 wc), LDS-staged A and B
// (global_load_lds w=16, XOR-swizzled source; swizzled ds_read -> conflict-free).
__global__ __launch_bounds__(256, 2) void score_pass_kernel(
    const u32* __restrict__ aggb, const u32* __restrict__ wwt_hi,
    const float* __restrict__ rs_in, const float* __restrict__ bsum,
    const float* __restrict__ wa2, float* __restrict__ evec,
    float* __restrict__ wvec) {
  __shared__ u32 As[8192];   // 128 rows x 16 chunks(16B), chunk ^= (row&7)
  __shared__ u32 Bs[8192];
  __shared__ float scoreS[NR][2][128];
  const int tid = threadIdx.x;
  const int l = tid & 63, w = tid >> 6;
  const int wr = w >> 1, wc = w & 1;
  const int l15 = l & 15, lg = l >> 4;
  const int row0 = blockIdx.x * 128;

  float wa2v[4];
#pragma unroll
  for (int nf = 0; nf < 4; ++nf) wa2v[nf] = wa2[wc * 64 + nf * 16 + l15];

  for (int r = 0; r < NR; ++r) {
    if (r) __syncthreads();
    const u32* Ar = aggb + (size_t)r * NN * 64;
    const u32* Br = wwt_hi + (size_t)r * 8192;
#pragma unroll
    for (int it = 0; it < 8; ++it) {
      int s = it * 256 + tid;            // 16B-chunk slot 0..2047
      int row = s >> 4;
      int c = (s & 15) ^ (row & 7);      // inverse-swizzled source chunk
      int grow = min(row0 + row, NN - 1);
      gload_lds16(Ar + (size_t)grow * 64 + c * 4, &As[it * 1024 + w * 256]);
      gload_lds16(Br + row * 64 + c * 4, &Bs[it * 1024 + w * 256]);
    }
    __syncthreads();

    f4_t c2[4][4];
#pragma unroll
    for (int rf = 0; rf < 4; ++rf)
#pragma unroll
      for (int nf = 0; nf < 4; ++nf) c2[rf][nf] = (f4_t)0.f;

#pragma unroll
    for (int ks = 0; ks < 4; ++ks) {
      bf8_t a[4];
#pragma unroll
      for (int rf = 0; rf < 4; ++rf) {
        int m = wr * 64 + rf * 16 + l15;
        int ch = (ks * 4 + lg) ^ (m & 7);
        a[rf] = ldfrag(&As[m * 64 + ch * 4]);
      }
#pragma unroll
      for (int nf = 0; nf < 4; ++nf) {
        int n = wc * 64 + nf * 16 + l15;
        int ch = (ks * 4 + lg) ^ (n & 7);
        bf8_t bb = ldfrag(&Bs[n * 64 + ch * 4]);
#pragma unroll
        for (int rf = 0; rf < 4; ++rf) c2[rf][nf] = MFMA(a[rf], bb, c2[rf][nf]);
      }
    }

    // epilogue: score partials
#pragma unroll
    for (int rf = 0; rf < 4; ++rf) {
      const int lr0 = wr * 64 + rf * 16 + lg * 4;
      float rsv[4];
#pragma unroll
      for (int reg = 0; reg < 4; ++reg)
        rsv[reg] = rs_in[r * NN + min(row0 + lr0 + reg, NN - 1)];
      float part[4] = {0.f, 0.f, 0.f, 0.f};
#pragma unroll
      for (int nf = 0; nf < 4; ++nf) {
        int col = wc * 64 + nf * 16 + l15;
        float bs = bsum[r * DD + col];
#pragma unroll
        for (int reg = 0; reg < 4; ++reg) {
          float t = fmaf(c2[rf][nf][reg], rsv[reg], bs);
          t = fminf(fmaxf(t, -15.f), 15.f);
          float ex = __expf(2.f * t);
          part[reg] = fmaf((ex - 1.f) / (ex + 1.f), wa2v[nf], part[reg]);
        }
      }
#pragma unroll
      for (int reg = 0; reg < 4; ++reg) {
        float p = part[reg];
        p += __shfl_xor(p, 1);
        p += __shfl_xor(p, 2);
        p += __shfl_xor(p, 4);
        p += __shfl_xor(p, 8);
        if (l15 == 0) scoreS[r][wc][lr0 + reg] = p;
      }
    }
  }
  __syncthreads();
  if (tid < 128) {
    int grow = row0 + tid;
    if (grow < NN) {
      float s0 = scoreS[0][0][tid] + scoreS[0][1][tid];
      float s1 = scoreS[1][0][tid] + scoreS[1][1][tid];
      float s2 = scoreS[2][0][tid] + scoreS[2][1][tid];
      float mx = fmaxf(s0, fmaxf(s1, s2));
      float e0 = __expf(s0 - mx), e1 = __expf(s1 - mx), e2 = __expf(s2 - mx);
      float inv = 1.f / (e0 + e1 + e2);
      e0 *= inv; e1 *= inv; e2 *= inv;
      evec[grow] = e0; evec[NN + grow] = e1; evec[2 * NN + grow] = e2;
      wvec[grow]          = e0 * rs_in[grow];
      wvec[NN + grow]     = e1 * rs_in[NN + grow];
      wvec[2 * NN + grow] = e2 * rs_in[2 * NN + grow];
    }
  }
}

// ============ pass 2: out = sum_r w_r*(agg_r @ W_r) + sum_r e_r*b_r ============
__global__ __launch_bounds__(256, 2) void out_pass_kernel(
    const u32* __restrict__ aggb, const u32* __restrict__ wt_hi,
    const u32* __restrict__ wt_lo, const float* __restrict__ evec,
    const float* __restrict__ wvec, const float* __restrict__ bias,
    float* __restrict__ out) {
  __shared__ u32 As[8192];
  __shared__ u32 Bs[8192];       // wt_hi (swizzled); wt_lo comes from global
  __shared__ float eL[NR][128];
  __shared__ float wfL[NR][128];
  __shared__ float bL[NR][128];
  const int tid = threadIdx.x;
  const int l = tid & 63, w = tid >> 6;
  const int wr = w >> 1, wc = w & 1;
  const int l15 = l & 15, lg = l >> 4;
  const int row0 = blockIdx.x * 128;

  // stage per-row softmax weights and bias (once, covered by first barrier)
  if (tid < 128) {
    int grow = min(row0 + tid, NN - 1);
#pragma unroll
    for (int r = 0; r < NR; ++r) {
      eL[r][tid]  = evec[r * NN + grow];
      wfL[r][tid] = wvec[r * NN + grow];
    }
  }
  for (int idx = tid; idx < NR * DD; idx += 256) bL[idx >> 7][idx & 127] = bias[idx];

  f4_t fo[4][4];

  for (int r = 0; r < NR; ++r) {
    if (r) __syncthreads();
    const u32* Ar = aggb + (size_t)r * NN * 64;
    const u32* Br = wt_hi + (size_t)r * 8192;
#pragma unroll
    for (int it = 0; it < 8; ++it) {
      int s = it * 256 + tid;
      int row = s >> 4;
      int c = (s & 15) ^ (row & 7);
      int grow = min(row0 + row, NN - 1);
      gload_lds16(Ar + (size_t)grow * 64 + c * 4, &As[it * 1024 + w * 256]);
      gload_lds16(Br + row * 64 + c * 4, &Bs[it * 1024 + w * 256]);
    }
    __syncthreads();

    if (r == 0) {
      // init accumulator with the softmax-weighted bias term
#pragma unroll
      for (int rf = 0; rf < 4; ++rf) {
        const int lr0 = wr * 64 + rf * 16 + lg * 4;
#pragma unroll
        for (int nf = 0; nf < 4; ++nf) {
          const int col = wc * 64 + nf * 16 + l15;
#pragma unroll
          for (int reg = 0; reg < 4; ++reg) {
            float v = eL[0][lr0 + reg] * bL[0][col];
            v = fmaf(eL[1][lr0 + reg], bL[1][col], v);
            v = fmaf(eL[2][lr0 + reg], bL[2][col], v);
            fo[rf][nf][reg] = v;
          }
        }
      }
    }

    f4_t cc[4][4];
#pragma unroll
    for (int rf = 0; rf < 4; ++rf)
#pragma unroll
      for (int nf = 0; nf < 4; ++nf) cc[rf][nf] = (f4_t)0.f;

#pragma unroll
    for (int ks = 0; ks < 4; ++ks) {
      bf8_t a[4];
#pragma unroll
      for (int rf = 0; rf < 4; ++rf) {
        int m = wr * 64 + rf * 16 + l15;
        int ch = (ks * 4 + lg) ^ (m & 7);
        a[rf] = ldfrag(&As[m * 64 + ch * 4]);
      }
#pragma unroll
      for (int nf = 0; nf < 4; ++nf) {
        int n = wc * 64 + nf * 16 + l15;
        int ch = (ks * 4 + lg) ^ (n & 7);
        bf8_t bh = ldfrag(&Bs[n * 64 + ch * 4]);
        bf8_t bl = ldfrag(wt_lo + (size_t)r * 8192 + n * 64 + (ks * 4 + lg) * 4);
#pragma unroll
        for (int rf = 0; rf < 4; ++rf) cc[rf][nf] = MFMA(a[rf], bh, cc[rf][nf]);
#pragma unroll
        for (int rf = 0; rf < 4; ++rf) cc[rf][nf] = MFMA(a[rf], bl, cc[rf][nf]);
      }
    }

    // fo += w_r(row) * cc
#pragma unroll
    for (int rf = 0; rf < 4; ++rf) {
      const int lr0 = wr * 64 + rf * 16 + lg * 4;
#pragma unroll
      for (int nf = 0; nf < 4; ++nf)
#pragma unroll
        for (int reg = 0; reg < 4; ++reg)
          fo[rf][nf][reg] = fmaf(cc[rf][nf][reg], wfL[r][lr0 + reg], fo[rf][nf][reg]);
    }
  }

  // store out (f32, natural C-fragment layout)
#pragma unroll
  for (int rf = 0; rf < 4; ++rf) {
#pragma unroll
    for (int reg = 0; reg < 4; ++reg) {
      int crow = row0 + wr * 64 + rf * 16 + lg * 4 + reg;
      if (crow < NN) {
#pragma unroll
        for (int nf = 0; nf < 4; ++nf)
          out[(size_t)crow * DD + wc * 64 + nf * 16 + l15] = fo[rf][nf][reg];
      }
    }
  }
}

extern "C" void kernel_launch(void* const* d_in, const int* in_sizes, int n_in,
                              void* d_out, int out_size, void* d_ws, size_t ws_size,
                              hipStream_t stream) {
  const float* x   = (const float*)d_in[0];
  const int*   src = (const int*)d_in[1];
  const int*   dst = (const int*)d_in[2];
  const float* W   = (const float*)d_in[3];
  const float* b   = (const float*)d_in[4];
  const float* Wa1 = (const float*)d_in[5];
  const float* ba1 = (const float*)d_in[6];
  const float* wa2 = (const float*)d_in[7];
  float* out = (float*)d_out;

  char* ws = (char*)d_ws;
  size_t off = 0;
  u32* aggb = (u32*)(ws + off); off += (size_t)NSEG * 64 * 4;   // 76.8 MB
  u32* xb   = (u32*)(ws + off); off += (size_t)NN * 64 * 4;     // 25.6 MB
  int* cnt_out = (int*)(ws + off); off += (size_t)NSEG * 4;
  int* cnt_in  = (int*)(ws + off); off += (size_t)NSEG * 4;
  float* rs_out = (float*)(ws + off); off += (size_t)NSEG * 4;
  float* rs_in  = (float*)(ws + off); off += (size_t)NSEG * 4;
  float* evec   = (float*)(ws + off); off += (size_t)NSEG * 4;
  float* wvec   = (float*)(ws + off); off += (size_t)NSEG * 4;
  int* offs    = (int*)(ws + off); off += (size_t)(NSEG + 4) * 4;
  int* cursor  = (int*)(ws + off); off += (size_t)NSEG * 4;
  int* blksum  = (int*)(ws + off); off += (size_t)512 * 4;
  int* esrc    = (int*)(ws + off); off += (size_t)NR * NE * 4;  // 7.68 MB
  float* WWa1  = (float*)(ws + off); off += (size_t)NR * DD * DD * 4;
  u32* wt_hi   = (u32*)(ws + off); off += (size_t)NR * DD * 64 * 4;
  u32* wt_lo   = (u32*)(ws + off); off += (size_t)NR * DD * 64 * 4;
  u32* wwt_hi  = (u32*)(ws + off); off += (size_t)NR * DD * 64 * 4;
  float* bsum  = (float*)(ws + off); off += (size_t)NR * DD * 4;
  if (ws_size < off) return;  // fail loudly (output stays poisoned)

  hipMemsetAsync(cnt_out, 0, (size_t)NSEG * 4 * 2, stream);  // cnt_out + cnt_in

  // weight prep (independent of graph chain)
  prep_wwa1_kernel<<<(NR * DD * DD + 255) / 256, 256, 0, stream>>>(W, Wa1, WWa1);
  prep_pack_kernel<<<(NR * DD * 64 + 255) / 256, 256, 0, stream>>>(W, WWa1, wt_hi, wt_lo,
                                                                   wwt_hi);
  prep_bsum_kernel<<<(NR * DD + 255) / 256, 256, 0, stream>>>(b, Wa1, ba1, bsum);

  convert_x_kernel<<<(NN * 64 + 255) / 256, 256, 0, stream>>>(x, xb);
  degree_kernel<<<(NR * NE + 255) / 256, 256, 0, stream>>>(src, dst, cnt_out, cnt_in);
  rs_kernel<<<(NSEG + 255) / 256, 256, 0, stream>>>(cnt_out, cnt_in, rs_out, rs_in);
  scan1_kernel<<<NBLK, 256, 0, stream>>>(cnt_in, offs, blksum);
  scan2_kernel<<<1, 512, 0, stream>>>(blksum, NBLK);
  scan3_kernel<<<(NSEG + 255) / 256, 256, 0, stream>>>(offs, blksum, cursor);
  fill_kernel<<<(NR * NE + 255) / 256, 256, 0, stream>>>(src, dst, cursor, esrc);
  aggregate_kernel<<<(NSEG + 15) / 16, 256, 0, stream>>>(xb, esrc, offs, rs_out, aggb);

  int gb = (NN + 127) / 128;
  score_pass_kernel<<<gb, 256, 0, stream>>>(aggb, wwt_hi, rs_in, bsum, wa2, evec, wvec);
  out_pass_kernel<<<gb, 256, 0, stream>>>(aggb, wt_hi, wt_lo, evec, wvec, b, out);
}